// Round 1
// baseline (668.970 us; speedup 1.0000x reference)
//
#include <hip/hip_runtime.h>

typedef unsigned short u16;
using s16x8 = __attribute__((ext_vector_type(8))) short;
using s16x4 = __attribute__((ext_vector_type(4))) short;
using u16x4 = __attribute__((ext_vector_type(4))) unsigned short;
using f32x4 = __attribute__((ext_vector_type(4))) float;

__device__ __forceinline__ u16 f2bf(float f) {
  unsigned int u = __float_as_uint(f);
  u += 0x7FFFu + ((u >> 16) & 1u);
  return (u16)(u >> 16);
}

// ---------------- conversion kernels ----------------
__global__ __launch_bounds__(256) void cvt4(const float* __restrict__ in,
                                            u16* __restrict__ out, int n4) {
  int i = blockIdx.x * 256 + threadIdx.x;
  if (i < n4) {
    float4 f = ((const float4*)in)[i];
    u16x4 o;
    o[0] = f2bf(f.x); o[1] = f2bf(f.y); o[2] = f2bf(f.z); o[3] = f2bf(f.w);
    ((u16x4*)out)[i] = o;
  }
}

__global__ __launch_bounds__(256) void transpose_bf16(const float* __restrict__ in,
                                                      u16* __restrict__ out,
                                                      int R, int C) {
  int idx = blockIdx.x * 256 + threadIdx.x;
  if (idx < R * C) {
    int r = idx / C, c = idx % C;
    out[(size_t)c * R + r] = f2bf(in[idx]);
  }
}

// ---------------- generic bf16 MFMA GEMM ----------------
// C(M,N) = A(M,K) * Bt(N,K)^T  [+bias] [+resid] [relu]
// MODE 0: bf16 out row-major. MODE 1: f32 out (+bias,+resid).
// MODE 2: QK scatter out[((n*8+h)*1024+l)*64+d]. MODE 3: V scatter out[((n*8+h)*64+d)*1024+l].
template <int MODE, bool RELU>
__global__ __launch_bounds__(256) void gemm64(const u16* __restrict__ A,
                                              const u16* __restrict__ Bt,
                                              const float* __restrict__ bias,
                                              const float* __restrict__ resid,
                                              void* __restrict__ outp,
                                              int M, int N, int K) {
  __shared__ __align__(16) u16 As[64][72];
  __shared__ __align__(16) u16 Bs[64][72];
  const int tid = threadIdx.x;
  const int m0 = blockIdx.y * 64, n0 = blockIdx.x * 64;
  const int lane = tid & 63, wid = tid >> 6;
  const int wm = (wid >> 1) * 32, wn = (wid & 1) * 32;

  f32x4 zero = {0.f, 0.f, 0.f, 0.f};
  f32x4 acc[2][2];
  acc[0][0] = zero; acc[0][1] = zero; acc[1][0] = zero; acc[1][1] = zero;

  const int r0 = tid >> 3, kc0 = (tid & 7) << 3;            // first chunk
  const int r1 = (tid + 256) >> 3, kc1 = ((tid + 256) & 7) << 3; // second chunk

  for (int k0 = 0; k0 < K; k0 += 64) {
    if (k0) __syncthreads();
    *(s16x8*)&As[r0][kc0] = *(const s16x8*)&A[(size_t)(m0 + r0) * K + k0 + kc0];
    *(s16x8*)&As[r1][kc1] = *(const s16x8*)&A[(size_t)(m0 + r1) * K + k0 + kc1];
    *(s16x8*)&Bs[r0][kc0] = *(const s16x8*)&Bt[(size_t)(n0 + r0) * K + k0 + kc0];
    *(s16x8*)&Bs[r1][kc1] = *(const s16x8*)&Bt[(size_t)(n0 + r1) * K + k0 + kc1];
    __syncthreads();
#pragma unroll
    for (int kk = 0; kk < 2; ++kk) {
      const int kb = kk * 32 + ((lane >> 4) << 3);
      s16x8 a0 = *(const s16x8*)&As[wm + (lane & 15)][kb];
      s16x8 a1 = *(const s16x8*)&As[wm + 16 + (lane & 15)][kb];
      s16x8 b0 = *(const s16x8*)&Bs[wn + (lane & 15)][kb];
      s16x8 b1 = *(const s16x8*)&Bs[wn + 16 + (lane & 15)][kb];
      acc[0][0] = __builtin_amdgcn_mfma_f32_16x16x32_bf16(a0, b0, acc[0][0], 0, 0, 0);
      acc[0][1] = __builtin_amdgcn_mfma_f32_16x16x32_bf16(a0, b1, acc[0][1], 0, 0, 0);
      acc[1][0] = __builtin_amdgcn_mfma_f32_16x16x32_bf16(a1, b0, acc[1][0], 0, 0, 0);
      acc[1][1] = __builtin_amdgcn_mfma_f32_16x16x32_bf16(a1, b1, acc[1][1], 0, 0, 0);
    }
  }

#pragma unroll
  for (int mf = 0; mf < 2; ++mf)
#pragma unroll
    for (int nf = 0; nf < 2; ++nf)
#pragma unroll
      for (int i = 0; i < 4; ++i) {
        int row = m0 + wm + mf * 16 + ((lane >> 4) << 2) + i;
        int col = n0 + wn + nf * 16 + (lane & 15);
        float v = acc[mf][nf][i];
        if (bias) v += bias[col];
        if (RELU) v = fmaxf(v, 0.f);
        if (MODE == 0) {
          ((u16*)outp)[(size_t)row * N + col] = f2bf(v);
        } else if (MODE == 1) {
          if (resid) v += resid[(size_t)row * N + col];
          ((float*)outp)[(size_t)row * N + col] = v;
        } else if (MODE == 2) {
          int l = row >> 3, n = row & 7, hh = col >> 6, d = col & 63;
          ((u16*)outp)[(((size_t)(n * 8 + hh) * 1024 + l) << 6) + d] = f2bf(v);
        } else {
          int l = row >> 3, n = row & 7, hh = col >> 6, d = col & 63;
          ((u16*)outp)[((size_t)(n * 8 + hh) * 64 + d) * 1024 + l] = f2bf(v);
        }
      }
}

// ---------------- fused attention: QK^T -> top-k mask -> softmax -> PV ----------------
// grid (L/16, 64). Qw/Kw: [nh][l][64] bf16. Vw: [nh][64][1024] bf16 (transposed).
// ao out: [t][d*8+h] bf16, t = l*8+n.
__global__ __launch_bounds__(256) void attn_kernel(const u16* __restrict__ Qw,
                                                   const u16* __restrict__ Kw,
                                                   const u16* __restrict__ Vw,
                                                   const float* __restrict__ topk,
                                                   u16* __restrict__ ao) {
  __shared__ __align__(16) float sc[16][1024];   // 64KB; P (bf16, swizzled) overlaid per-row
  __shared__ __align__(16) u16 Qt[16][72];
  const int tid = threadIdx.x, lane = tid & 63, wid = tid >> 6;
  const int mb = blockIdx.x, nh = blockIdx.y;

  const int kkeep = (int)(1024.f / (1.f + expf(-topk[0])));

  // stage Q tile (16 x 64)
  {
    int r = tid >> 4, dc = (tid & 15) << 2;
    *(s16x4*)&Qt[r][dc] =
        *(const s16x4*)&Qw[((size_t)nh * 1024 + mb * 16 + r) * 64 + dc];
  }
  __syncthreads();

  // ---- Phase A: scores = Q K^T / 8, wave w covers s in [256w, 256w+256) ----
  {
    const u16* Kb = Kw + (size_t)nh * 1024 * 64;
    s16x8 aq[2];
#pragma unroll
    for (int kk = 0; kk < 2; ++kk)
      aq[kk] = *(const s16x8*)&Qt[lane & 15][kk * 32 + ((lane >> 4) << 3)];
    const int s0 = wid * 256;
    f32x4 acc[16];
    f32x4 zero = {0.f, 0.f, 0.f, 0.f};
#pragma unroll
    for (int nf = 0; nf < 16; ++nf) acc[nf] = zero;
#pragma unroll
    for (int nf = 0; nf < 16; ++nf) {
      int sr = s0 + nf * 16 + (lane & 15);
#pragma unroll
      for (int kk = 0; kk < 2; ++kk) {
        s16x8 b = *(const s16x8*)&Kb[(size_t)sr * 64 + kk * 32 + ((lane >> 4) << 3)];
        acc[nf] = __builtin_amdgcn_mfma_f32_16x16x32_bf16(aq[kk], b, acc[nf], 0, 0, 0);
      }
    }
#pragma unroll
    for (int nf = 0; nf < 16; ++nf)
#pragma unroll
      for (int i = 0; i < 4; ++i)
        sc[((lane >> 4) << 2) + i][s0 + nf * 16 + (lane & 15)] = acc[nf][i] * 0.125f;
  }
  __syncthreads();

  // ---- Phase B: per-row top-k threshold (588th largest) + softmax, write P bf16 ----
  for (int rr = 0; rr < 4; ++rr) {
    const int r = wid * 4 + rr;
    float v[16];
    unsigned int key[16];
#pragma unroll
    for (int j = 0; j < 16; ++j) {
      v[j] = sc[r][lane + 64 * j];
      unsigned int u = __float_as_uint(v[j]);
      key[j] = u ^ ((u >> 31) ? 0xFFFFFFFFu : 0x80000000u);
    }
    unsigned int T = 0;
    for (int bit = 31; bit >= 0; --bit) {
      unsigned int cand = T | (1u << bit);
      int c = 0;
#pragma unroll
      for (int j = 0; j < 16; ++j) c += (key[j] >= cand) ? 1 : 0;
      c += __shfl_xor(c, 1); c += __shfl_xor(c, 2); c += __shfl_xor(c, 4);
      c += __shfl_xor(c, 8); c += __shfl_xor(c, 16); c += __shfl_xor(c, 32);
      if (c >= kkeep) T = cand;
    }
    float m = v[0];
#pragma unroll
    for (int j = 1; j < 16; ++j) m = fmaxf(m, v[j]);
    m = fmaxf(m, __shfl_xor(m, 1)); m = fmaxf(m, __shfl_xor(m, 2));
    m = fmaxf(m, __shfl_xor(m, 4)); m = fmaxf(m, __shfl_xor(m, 8));
    m = fmaxf(m, __shfl_xor(m, 16)); m = fmaxf(m, __shfl_xor(m, 32));
    float e[16];
    float sum = 0.f;
#pragma unroll
    for (int j = 0; j < 16; ++j) {
      e[j] = (key[j] >= T) ? __expf(v[j] - m) : 0.f;
      sum += e[j];
    }
    sum += __shfl_xor(sum, 1); sum += __shfl_xor(sum, 2); sum += __shfl_xor(sum, 4);
    sum += __shfl_xor(sum, 8); sum += __shfl_xor(sum, 16); sum += __shfl_xor(sum, 32);
    const float inv = 1.f / sum;
    char* Prow = (char*)&sc[r][0];
    const int X = (r & 7) << 4;
#pragma unroll
    for (int j = 0; j < 16; ++j) {
      int s = lane + 64 * j;
      *(u16*)(Prow + ((2 * s) ^ X)) = f2bf(e[j] * inv);
    }
  }
  __syncthreads();

  // ---- Phase C: out = P @ V, wave w owns d in [16w, 16w+16) ----
  {
    const u16* Vb = Vw + (size_t)nh * 64 * 1024;
    const int d0 = wid * 16;
    f32x4 oacc = {0.f, 0.f, 0.f, 0.f};
    const int pr = lane & 15;
    const char* Pbase = (const char*)&sc[pr][0];
    const int X = (pr & 7) << 4;
#pragma unroll 4
    for (int ks = 0; ks < 32; ++ks) {
      int kbyte = (ks * 64 + ((lane >> 4) << 4)) ^ X;
      s16x8 a = *(const s16x8*)(Pbase + kbyte);
      s16x8 b = *(const s16x8*)&Vb[(size_t)(d0 + (lane & 15)) * 1024 + ks * 32 +
                                   ((lane >> 4) << 3)];
      oacc = __builtin_amdgcn_mfma_f32_16x16x32_bf16(a, b, oacc, 0, 0, 0);
    }
    const int n = nh >> 3, hh = nh & 7;
#pragma unroll
    for (int i = 0; i < 4; ++i) {
      int l = mb * 16 + ((lane >> 4) << 2) + i;
      int d = d0 + (lane & 15);
      ao[(size_t)(l * 8 + n) * 512 + d * 8 + hh] = f2bf(oacc[i]);
    }
  }
}

// ---------------- LayerNorm over rows of 512 ----------------
__global__ __launch_bounds__(256) void ln_kernel(const float* __restrict__ x,
                                                 const float* __restrict__ g,
                                                 const float* __restrict__ b,
                                                 float* __restrict__ of,
                                                 u16* __restrict__ ob) {
  __shared__ float red[8];
  const int t = blockIdx.x, tid = threadIdx.x;
  const int lane = tid & 63, wid = tid >> 6;
  const float* xr = x + (size_t)t * 512;
  float x0 = xr[tid], x1 = xr[tid + 256];
  float s = x0 + x1;
#pragma unroll
  for (int off = 32; off; off >>= 1) s += __shfl_xor(s, off);
  if (lane == 0) red[wid] = s;
  __syncthreads();
  const float mean = (red[0] + red[1] + red[2] + red[3]) * (1.f / 512.f);
  const float d0 = x0 - mean, d1 = x1 - mean;
  float q2 = d0 * d0 + d1 * d1;
#pragma unroll
  for (int off = 32; off; off >>= 1) q2 += __shfl_xor(q2, off);
  if (lane == 0) red[4 + wid] = q2;
  __syncthreads();
  const float var = (red[4] + red[5] + red[6] + red[7]) * (1.f / 512.f);
  const float inv = rsqrtf(var + 1e-5f);
  const float y0 = d0 * inv * g[tid] + b[tid];
  const float y1 = d1 * inv * g[tid + 256] + b[tid + 256];
  if (of) {
    of[(size_t)t * 512 + tid] = y0;
    of[(size_t)t * 512 + tid + 256] = y1;
  }
  if (ob) {
    ob[(size_t)t * 512 + tid] = f2bf(y0);
    ob[(size_t)t * 512 + tid + 256] = f2bf(y1);
  }
}

// ---------------- host launch ----------------
extern "C" void kernel_launch(void* const* d_in, const int* in_sizes, int n_in,
                              void* d_out, int out_size, void* d_ws, size_t ws_size,
                              hipStream_t stream) {
  const float* q = (const float*)d_in[0];
  const float* k = (const float*)d_in[1];
  const float* v = (const float*)d_in[2];
  const float* Wq = (const float*)d_in[3];
  const float* bq = (const float*)d_in[4];
  const float* Wk = (const float*)d_in[5];
  const float* bk = (const float*)d_in[6];
  const float* Wv = (const float*)d_in[7];
  const float* bv = (const float*)d_in[8];
  const float* Wo = (const float*)d_in[9];
  const float* bo = (const float*)d_in[10];
  const float* topk = (const float*)d_in[11];
  const float* A1 = (const float*)d_in[12];
  const float* B1 = (const float*)d_in[13];
  const float* A2 = (const float*)d_in[14];
  const float* B2 = (const float*)d_in[15];
  const float* g1 = (const float*)d_in[16];
  const float* be1 = (const float*)d_in[17];
  const float* g2 = (const float*)d_in[18];
  const float* be2 = (const float*)d_in[19];

  char* ws = (char*)d_ws;
  constexpr size_t SZ_TOK_BF = (size_t)8192 * 512 * 2;  // 8,388,608
  constexpr size_t SZ_W_BF = (size_t)512 * 512 * 2;     // 524,288
  constexpr size_t O_QB = 0;
  constexpr size_t O_KB = O_QB + SZ_TOK_BF;
  constexpr size_t O_VB = O_KB + SZ_TOK_BF;
  constexpr size_t O_QW = O_VB + SZ_TOK_BF;
  constexpr size_t O_KW = O_QW + SZ_TOK_BF;
  constexpr size_t O_VW = O_KW + SZ_TOK_BF;
  constexpr size_t O_WQT = O_VW + SZ_TOK_BF;
  constexpr size_t O_WKT = O_WQT + SZ_W_BF;
  constexpr size_t O_WVT = O_WKT + SZ_W_BF;
  constexpr size_t O_WOT = O_WVT + SZ_W_BF;
  constexpr size_t O_A1T = O_WOT + SZ_W_BF;
  constexpr size_t O_B1T = O_A1T + 65536;
  constexpr size_t O_A2T = O_B1T + 262144;
  constexpr size_t O_B2T = O_A2T + 262144;
  constexpr size_t O_AO = O_B2T + 65536;
  constexpr size_t O_Y = O_AO + SZ_TOK_BF;
  constexpr size_t O_SRCF = O_Y + (size_t)8192 * 512 * 4;
  constexpr size_t O_SRCB = O_SRCF + (size_t)8192 * 512 * 4;
  constexpr size_t O_U = O_SRCB + SZ_TOK_BF;
  constexpr size_t O_W2 = O_U + (size_t)8192 * 64 * 2;
  constexpr size_t O_H = 0;  // overlays qb/kb/vb/Qw (dead by the time FFN runs)

  u16* qb = (u16*)(ws + O_QB);
  u16* kb = (u16*)(ws + O_KB);
  u16* vb = (u16*)(ws + O_VB);
  u16* Qw_ = (u16*)(ws + O_QW);
  u16* Kw_ = (u16*)(ws + O_KW);
  u16* Vw_ = (u16*)(ws + O_VW);
  u16* WqT = (u16*)(ws + O_WQT);
  u16* WkT = (u16*)(ws + O_WKT);
  u16* WvT = (u16*)(ws + O_WVT);
  u16* WoT = (u16*)(ws + O_WOT);
  u16* A1T = (u16*)(ws + O_A1T);
  u16* B1T = (u16*)(ws + O_B1T);
  u16* A2T = (u16*)(ws + O_A2T);
  u16* B2T = (u16*)(ws + O_B2T);
  u16* ao = (u16*)(ws + O_AO);
  float* y = (float*)(ws + O_Y);
  float* srcf = (float*)(ws + O_SRCF);
  u16* srcb = (u16*)(ws + O_SRCB);
  u16* ubuf = (u16*)(ws + O_U);
  u16* w2 = (u16*)(ws + O_W2);
  u16* hbuf = (u16*)(ws + O_H);

  // 1) convert q,k,v to bf16
  cvt4<<<4096, 256, 0, stream>>>(q, qb, 1048576);
  cvt4<<<4096, 256, 0, stream>>>(k, kb, 1048576);
  cvt4<<<4096, 256, 0, stream>>>(v, vb, 1048576);
  // 2) transpose+convert weights (Bt layouts)
  transpose_bf16<<<1024, 256, 0, stream>>>(Wq, WqT, 512, 512);
  transpose_bf16<<<1024, 256, 0, stream>>>(Wk, WkT, 512, 512);
  transpose_bf16<<<1024, 256, 0, stream>>>(Wv, WvT, 512, 512);
  transpose_bf16<<<1024, 256, 0, stream>>>(Wo, WoT, 512, 512);
  transpose_bf16<<<128, 256, 0, stream>>>(A1, A1T, 512, 64);
  transpose_bf16<<<512, 256, 0, stream>>>(B1, B1T, 64, 2048);
  transpose_bf16<<<512, 256, 0, stream>>>(A2, A2T, 2048, 64);
  transpose_bf16<<<128, 256, 0, stream>>>(B2, B2T, 64, 512);

  // 3) QKV projections with head-scatter epilogues
  gemm64<2, false><<<dim3(8, 128), 256, 0, stream>>>(qb, WqT, bq, nullptr, Qw_, 8192, 512, 512);
  gemm64<2, false><<<dim3(8, 128), 256, 0, stream>>>(kb, WkT, bk, nullptr, Kw_, 8192, 512, 512);
  gemm64<3, false><<<dim3(8, 128), 256, 0, stream>>>(vb, WvT, bv, nullptr, Vw_, 8192, 512, 512);

  // 4) fused attention (QK^T, top-k threshold, softmax, PV)
  attn_kernel<<<dim3(64, 64), 256, 0, stream>>>(Qw_, Kw_, Vw_, topk, ao);

  // 5) Wo projection + bias + residual(q) -> y (f32)
  gemm64<1, false><<<dim3(8, 128), 256, 0, stream>>>(ao, WoT, bo, q, y, 8192, 512, 512);

  // 6) LN1 -> srcf (f32) + srcb (bf16)
  ln_kernel<<<8192, 256, 0, stream>>>(y, g1, be1, srcf, srcb);

  // 7) FFN: u = src@A1 ; h = relu(u@B1) ; w2 = h@A2 ; y = w2@B2 + srcf
  gemm64<0, false><<<dim3(1, 128), 256, 0, stream>>>(srcb, A1T, nullptr, nullptr, ubuf, 8192, 64, 512);
  gemm64<0, true><<<dim3(32, 128), 256, 0, stream>>>(ubuf, B1T, nullptr, nullptr, hbuf, 8192, 2048, 64);
  gemm64<0, false><<<dim3(1, 128), 256, 0, stream>>>(hbuf, A2T, nullptr, nullptr, w2, 8192, 64, 2048);
  gemm64<1, false><<<dim3(8, 128), 256, 0, stream>>>(w2, B2T, nullptr, srcf, y, 8192, 512, 64);

  // 8) LN2 -> d_out (f32)
  ln_kernel<<<8192, 256, 0, stream>>>(y, g2, be2, (float*)d_out, nullptr);
}

// Round 2
// 359.393 us; speedup vs baseline: 1.8614x; 1.8614x over previous
//
#include <hip/hip_runtime.h>

typedef unsigned short u16;
typedef unsigned int u32;
using s16x8 = __attribute__((ext_vector_type(8))) short;
using s16x4 = __attribute__((ext_vector_type(4))) short;
using u16x4 = __attribute__((ext_vector_type(4))) unsigned short;
using u32x4 = __attribute__((ext_vector_type(4))) unsigned int;
using f32x4 = __attribute__((ext_vector_type(4))) float;

__device__ __forceinline__ u16 f2bf(float f) {
  unsigned int u = __float_as_uint(f);
  u += 0x7FFFu + ((u >> 16) & 1u);
  return (u16)(u >> 16);
}

// monotone 16-bit key from f32 (sign-flip trick, truncated)
__device__ __forceinline__ u32 f2key(float f) {
  u32 u = __float_as_uint(f);
  u32 flip = (u32)((int)u >> 31) | 0x80000000u;
  return (u ^ flip) >> 16;
}
// inverse: 16-bit key -> f32 (truncated value)
__device__ __forceinline__ float key2f(u32 k) {
  u32 fl = 0x8000u | ((((k >> 15) & 1u) - 1u) & 0x7FFFu);
  return __uint_as_float(((k ^ fl) & 0xFFFFu) << 16);
}

// ---------------- conversion kernels ----------------
__global__ __launch_bounds__(256) void cvt4(const float* __restrict__ in,
                                            u16* __restrict__ out, int n4) {
  int i = blockIdx.x * 256 + threadIdx.x;
  if (i < n4) {
    float4 f = ((const float4*)in)[i];
    u16x4 o;
    o[0] = f2bf(f.x); o[1] = f2bf(f.y); o[2] = f2bf(f.z); o[3] = f2bf(f.w);
    ((u16x4*)out)[i] = o;
  }
}

__global__ __launch_bounds__(256) void transpose_bf16(const float* __restrict__ in,
                                                      u16* __restrict__ out,
                                                      int R, int C) {
  int idx = blockIdx.x * 256 + threadIdx.x;
  if (idx < R * C) {
    int r = idx / C, c = idx % C;
    out[(size_t)c * R + r] = f2bf(in[idx]);
  }
}

// ---------------- generic bf16 MFMA GEMM ----------------
// C(M,N) = A(M,K) * Bt(N,K)^T  [+bias] [+resid] [relu]
// MODE 0: bf16 out row-major. MODE 1: f32 out (+bias,+resid).
// MODE 2: QK scatter out[((n*8+h)*1024+l)*64+d]. MODE 3: V scatter out[((n*8+h)*64+d)*1024+l].
template <int MODE, bool RELU>
__global__ __launch_bounds__(256) void gemm64(const u16* __restrict__ A,
                                              const u16* __restrict__ Bt,
                                              const float* __restrict__ bias,
                                              const float* __restrict__ resid,
                                              void* __restrict__ outp,
                                              int M, int N, int K) {
  __shared__ __align__(16) u16 As[64][72];
  __shared__ __align__(16) u16 Bs[64][72];
  const int tid = threadIdx.x;
  const int m0 = blockIdx.y * 64, n0 = blockIdx.x * 64;
  const int lane = tid & 63, wid = tid >> 6;
  const int wm = (wid >> 1) * 32, wn = (wid & 1) * 32;

  f32x4 zero = {0.f, 0.f, 0.f, 0.f};
  f32x4 acc[2][2];
  acc[0][0] = zero; acc[0][1] = zero; acc[1][0] = zero; acc[1][1] = zero;

  const int r0 = tid >> 3, kc0 = (tid & 7) << 3;
  const int r1 = (tid + 256) >> 3, kc1 = ((tid + 256) & 7) << 3;

  for (int k0 = 0; k0 < K; k0 += 64) {
    if (k0) __syncthreads();
    *(s16x8*)&As[r0][kc0] = *(const s16x8*)&A[(size_t)(m0 + r0) * K + k0 + kc0];
    *(s16x8*)&As[r1][kc1] = *(const s16x8*)&A[(size_t)(m0 + r1) * K + k0 + kc1];
    *(s16x8*)&Bs[r0][kc0] = *(const s16x8*)&Bt[(size_t)(n0 + r0) * K + k0 + kc0];
    *(s16x8*)&Bs[r1][kc1] = *(const s16x8*)&Bt[(size_t)(n0 + r1) * K + k0 + kc1];
    __syncthreads();
#pragma unroll
    for (int kk = 0; kk < 2; ++kk) {
      const int kb = kk * 32 + ((lane >> 4) << 3);
      s16x8 a0 = *(const s16x8*)&As[wm + (lane & 15)][kb];
      s16x8 a1 = *(const s16x8*)&As[wm + 16 + (lane & 15)][kb];
      s16x8 b0 = *(const s16x8*)&Bs[wn + (lane & 15)][kb];
      s16x8 b1 = *(const s16x8*)&Bs[wn + 16 + (lane & 15)][kb];
      acc[0][0] = __builtin_amdgcn_mfma_f32_16x16x32_bf16(a0, b0, acc[0][0], 0, 0, 0);
      acc[0][1] = __builtin_amdgcn_mfma_f32_16x16x32_bf16(a0, b1, acc[0][1], 0, 0, 0);
      acc[1][0] = __builtin_amdgcn_mfma_f32_16x16x32_bf16(a1, b0, acc[1][0], 0, 0, 0);
      acc[1][1] = __builtin_amdgcn_mfma_f32_16x16x32_bf16(a1, b1, acc[1][1], 0, 0, 0);
    }
  }

#pragma unroll
  for (int mf = 0; mf < 2; ++mf)
#pragma unroll
    for (int nf = 0; nf < 2; ++nf)
#pragma unroll
      for (int i = 0; i < 4; ++i) {
        int row = m0 + wm + mf * 16 + ((lane >> 4) << 2) + i;
        int col = n0 + wn + nf * 16 + (lane & 15);
        float v = acc[mf][nf][i];
        if (bias) v += bias[col];
        if (RELU) v = fmaxf(v, 0.f);
        if (MODE == 0) {
          ((u16*)outp)[(size_t)row * N + col] = f2bf(v);
        } else if (MODE == 1) {
          if (resid) v += resid[(size_t)row * N + col];
          ((float*)outp)[(size_t)row * N + col] = v;
        } else if (MODE == 2) {
          int l = row >> 3, n = row & 7, hh = col >> 6, d = col & 63;
          ((u16*)outp)[(((size_t)(n * 8 + hh) * 1024 + l) << 6) + d] = f2bf(v);
        } else {
          int l = row >> 3, n = row & 7, hh = col >> 6, d = col & 63;
          ((u16*)outp)[((size_t)(n * 8 + hh) * 64 + d) * 1024 + l] = f2bf(v);
        }
      }
}

// ---------------- fused attention: QK^T -> top-k mask -> softmax -> PV ----------------
// grid (L/16, 64). Qw/Kw: [nh][l][64] bf16. Vw: [nh][64][1024] bf16 (transposed).
// ao out: [t][d*8+h] bf16, t = l*8+n.
// Score keys (16-bit monotone) live in scb (swizzled); replaced in-place by
// unnormalized P (bf16); 1/sum folded into PV epilogue via invs[].
__global__ __launch_bounds__(256, 4) void attn_kernel(const u16* __restrict__ Qw,
                                                      const u16* __restrict__ Kw,
                                                      const u16* __restrict__ Vw,
                                                      const float* __restrict__ topk,
                                                      u16* __restrict__ ao) {
  __shared__ __align__(16) u16 scb[16 * 1024];  // 32KB: keys -> P (bf16), XOR-swizzled
  __shared__ __align__(16) u16 Qt[16][72];
  __shared__ float invs[16];
  const int tid = threadIdx.x, lane = tid & 63, wid = tid >> 6;
  const int l16 = lane & 15, hi = lane >> 4;
  const int mb = blockIdx.x, nh = blockIdx.y;

  const int kkeep = (int)(1024.f / (1.f + __expf(-topk[0])));

  // stage Q tile (16 x 64)
  {
    int r = tid >> 4, dc = (tid & 15) << 2;
    *(s16x4*)&Qt[r][dc] =
        *(const s16x4*)&Qw[((size_t)nh * 1024 + mb * 16 + r) * 64 + dc];
  }
  __syncthreads();

  // ---- Phase A: keys = key(QK^T/8); swapped mfma(K,Q) so lane's 4 acc vals are
  // consecutive s for one q-row -> packed b64 key writes. Wave w: s in [256w,256w+256).
  {
    const u16* Kb = Kw + (size_t)nh * 1024 * 64;
    s16x8 bq0 = *(const s16x8*)&Qt[l16][hi * 8];
    s16x8 bq1 = *(const s16x8*)&Qt[l16][32 + hi * 8];
    const int s0 = wid * 256;
    const int Xq = (l16 & 7) << 4;
    char* rowq = (char*)scb + l16 * 2048;
#pragma unroll
    for (int nf = 0; nf < 16; ++nf) {
      const int sr = s0 + nf * 16 + l16;
      f32x4 acc = {0.f, 0.f, 0.f, 0.f};
      s16x8 a0 = *(const s16x8*)&Kb[(size_t)sr * 64 + hi * 8];
      s16x8 a1 = *(const s16x8*)&Kb[(size_t)sr * 64 + 32 + hi * 8];
      acc = __builtin_amdgcn_mfma_f32_16x16x32_bf16(a0, bq0, acc, 0, 0, 0);
      acc = __builtin_amdgcn_mfma_f32_16x16x32_bf16(a1, bq1, acc, 0, 0, 0);
      // acc[i] = score for (q = l16, s = s0 + 16*nf + 4*hi + i)
      u32 k0 = f2key(acc[0] * 0.125f) | (f2key(acc[1] * 0.125f) << 16);
      u32 k1 = f2key(acc[2] * 0.125f) | (f2key(acc[3] * 0.125f) << 16);
      int boff = (2 * (s0 + nf * 16 + 4 * hi)) ^ Xq;
      *(uint2*)(rowq + boff) = make_uint2(k0, k1);
    }
  }
  __syncthreads();

  // ---- Phase B: per-row top-k (SWAR radix search on 15-bit keys) + softmax.
  // 16-lane group g owns row wid*4+g; 64 keys/lane.
  {
    const int row = wid * 4 + hi;
    const int Xr = (row & 7) << 4;
    char* rowb = (char*)scb + row * 2048;
    u32 dw[32];
#pragma unroll
    for (int c = 0; c < 8; ++c)
      *(u32x4*)&dw[4 * c] = *(const u32x4*)(rowb + ((16 * l16 + 256 * c) ^ Xr));
    u32 dp[32];
#pragma unroll
    for (int i = 0; i < 32; ++i) dp[i] = (dw[i] & 0xFFFEFFFEu) >> 1;

    u32 T = 0;
#pragma unroll
    for (int bit = 14; bit >= 0; --bit) {
      u32 cand = T + (1u << bit);
      u32 cc = 0x80008000u - ((cand << 16) | cand);
      u32 acc = 0;
#pragma unroll
      for (int i = 0; i < 32; ++i) acc += ((dp[i] + cc) >> 15) & 0x00010001u;
      int cnt = (int)((acc & 0xFFFFu) + (acc >> 16));
      cnt += __shfl_xor(cnt, 1); cnt += __shfl_xor(cnt, 2);
      cnt += __shfl_xor(cnt, 4); cnt += __shfl_xor(cnt, 8);
      if (cnt >= kkeep) T = cand;
    }

    // max key (always kept) -> m
    u32 mx = 0;
#pragma unroll
    for (int i = 0; i < 32; ++i) {
      mx = max(mx, dw[i] << 16);
      mx = max(mx, dw[i] & 0xFFFF0000u);
    }
    mx = max(mx, (u32)__shfl_xor((int)mx, 1));
    mx = max(mx, (u32)__shfl_xor((int)mx, 2));
    mx = max(mx, (u32)__shfl_xor((int)mx, 4));
    mx = max(mx, (u32)__shfl_xor((int)mx, 8));
    const float mval = key2f(mx >> 16);
    const u32 T2 = T << 1;  // keep iff key16 >= T2  (== key16>>1 >= T)

    float sum = 0.f;
#pragma unroll
    for (int c = 0; c < 8; ++c) {
      u32 outw[4];
#pragma unroll
      for (int t = 0; t < 4; ++t) {
        u32 w = dw[4 * c + t];
        u32 klo = w & 0xFFFFu, khi = w >> 16;
        float vlo = key2f(klo), vhi = key2f(khi);
        float elo = (klo >= T2) ? __expf(vlo - mval) : 0.f;
        float ehi = (khi >= T2) ? __expf(vhi - mval) : 0.f;
        sum += elo + ehi;
        outw[t] = (u32)f2bf(elo) | ((u32)f2bf(ehi) << 16);
      }
      *(u32x4*)(rowb + ((16 * l16 + 256 * c) ^ Xr)) = *(u32x4*)outw;
    }
    sum += __shfl_xor(sum, 1); sum += __shfl_xor(sum, 2);
    sum += __shfl_xor(sum, 4); sum += __shfl_xor(sum, 8);
    if (l16 == 0) invs[row] = __builtin_amdgcn_rcpf(sum);
  }
  __syncthreads();

  // ---- Phase C: out = (P @ V) * inv, wave w owns d in [16w, 16w+16) ----
  {
    const u16* Vb = Vw + (size_t)nh * 64 * 1024;
    const int d0 = wid * 16;
    f32x4 oacc0 = {0.f, 0.f, 0.f, 0.f};
    f32x4 oacc1 = {0.f, 0.f, 0.f, 0.f};
    const int pr = l16;
    const char* Pbase = (const char*)scb + pr * 2048;
    const int Xp = (pr & 7) << 4;
#pragma unroll
    for (int ks = 0; ks < 32; ks += 2) {
      int kb0 = (ks * 64 + hi * 16) ^ Xp;
      int kb1 = ((ks + 1) * 64 + hi * 16) ^ Xp;
      s16x8 a0 = *(const s16x8*)(Pbase + kb0);
      s16x8 a1 = *(const s16x8*)(Pbase + kb1);
      s16x8 b0 = *(const s16x8*)&Vb[(size_t)(d0 + l16) * 1024 + ks * 32 + hi * 8];
      s16x8 b1 = *(const s16x8*)&Vb[(size_t)(d0 + l16) * 1024 + (ks + 1) * 32 + hi * 8];
      oacc0 = __builtin_amdgcn_mfma_f32_16x16x32_bf16(a0, b0, oacc0, 0, 0, 0);
      oacc1 = __builtin_amdgcn_mfma_f32_16x16x32_bf16(a1, b1, oacc1, 0, 0, 0);
    }
    const int n = nh >> 3, hh = nh & 7;
#pragma unroll
    for (int i = 0; i < 4; ++i) {
      int l = mb * 16 + hi * 4 + i;
      int d = d0 + l16;
      float v = (oacc0[i] + oacc1[i]) * invs[hi * 4 + i];
      ao[(size_t)(l * 8 + n) * 512 + d * 8 + hh] = f2bf(v);
    }
  }
}

// ---------------- LayerNorm over rows of 512 ----------------
__global__ __launch_bounds__(256) void ln_kernel(const float* __restrict__ x,
                                                 const float* __restrict__ g,
                                                 const float* __restrict__ b,
                                                 float* __restrict__ of,
                                                 u16* __restrict__ ob) {
  __shared__ float red[8];
  const int t = blockIdx.x, tid = threadIdx.x;
  const int lane = tid & 63, wid = tid >> 6;
  const float* xr = x + (size_t)t * 512;
  float x0 = xr[tid], x1 = xr[tid + 256];
  float s = x0 + x1;
#pragma unroll
  for (int off = 32; off; off >>= 1) s += __shfl_xor(s, off);
  if (lane == 0) red[wid] = s;
  __syncthreads();
  const float mean = (red[0] + red[1] + red[2] + red[3]) * (1.f / 512.f);
  const float d0 = x0 - mean, d1 = x1 - mean;
  float q2 = d0 * d0 + d1 * d1;
#pragma unroll
  for (int off = 32; off; off >>= 1) q2 += __shfl_xor(q2, off);
  if (lane == 0) red[4 + wid] = q2;
  __syncthreads();
  const float var = (red[4] + red[5] + red[6] + red[7]) * (1.f / 512.f);
  const float inv = rsqrtf(var + 1e-5f);
  const float y0 = d0 * inv * g[tid] + b[tid];
  const float y1 = d1 * inv * g[tid + 256] + b[tid + 256];
  if (of) {
    of[(size_t)t * 512 + tid] = y0;
    of[(size_t)t * 512 + tid + 256] = y1;
  }
  if (ob) {
    ob[(size_t)t * 512 + tid] = f2bf(y0);
    ob[(size_t)t * 512 + tid + 256] = f2bf(y1);
  }
}

// ---------------- host launch ----------------
extern "C" void kernel_launch(void* const* d_in, const int* in_sizes, int n_in,
                              void* d_out, int out_size, void* d_ws, size_t ws_size,
                              hipStream_t stream) {
  const float* q = (const float*)d_in[0];
  const float* k = (const float*)d_in[1];
  const float* v = (const float*)d_in[2];
  const float* Wq = (const float*)d_in[3];
  const float* bq = (const float*)d_in[4];
  const float* Wk = (const float*)d_in[5];
  const float* bk = (const float*)d_in[6];
  const float* Wv = (const float*)d_in[7];
  const float* bv = (const float*)d_in[8];
  const float* Wo = (const float*)d_in[9];
  const float* bo = (const float*)d_in[10];
  const float* topk = (const float*)d_in[11];
  const float* A1 = (const float*)d_in[12];
  const float* B1 = (const float*)d_in[13];
  const float* A2 = (const float*)d_in[14];
  const float* B2 = (const float*)d_in[15];
  const float* g1 = (const float*)d_in[16];
  const float* be1 = (const float*)d_in[17];
  const float* g2 = (const float*)d_in[18];
  const float* be2 = (const float*)d_in[19];

  char* ws = (char*)d_ws;
  constexpr size_t SZ_TOK_BF = (size_t)8192 * 512 * 2;
  constexpr size_t SZ_W_BF = (size_t)512 * 512 * 2;
  constexpr size_t O_QB = 0;
  constexpr size_t O_KB = O_QB + SZ_TOK_BF;
  constexpr size_t O_VB = O_KB + SZ_TOK_BF;
  constexpr size_t O_QW = O_VB + SZ_TOK_BF;
  constexpr size_t O_KW = O_QW + SZ_TOK_BF;
  constexpr size_t O_VW = O_KW + SZ_TOK_BF;
  constexpr size_t O_WQT = O_VW + SZ_TOK_BF;
  constexpr size_t O_WKT = O_WQT + SZ_W_BF;
  constexpr size_t O_WVT = O_WKT + SZ_W_BF;
  constexpr size_t O_WOT = O_WVT + SZ_W_BF;
  constexpr size_t O_A1T = O_WOT + SZ_W_BF;
  constexpr size_t O_B1T = O_A1T + 65536;
  constexpr size_t O_A2T = O_B1T + 262144;
  constexpr size_t O_B2T = O_A2T + 262144;
  constexpr size_t O_AO = O_B2T + 65536;
  constexpr size_t O_Y = O_AO + SZ_TOK_BF;
  constexpr size_t O_SRCF = O_Y + (size_t)8192 * 512 * 4;
  constexpr size_t O_SRCB = O_SRCF + (size_t)8192 * 512 * 4;
  constexpr size_t O_U = O_SRCB + SZ_TOK_BF;
  constexpr size_t O_W2 = O_U + (size_t)8192 * 64 * 2;
  constexpr size_t O_H = 0;  // overlays qb/kb/vb (dead by FFN time)

  u16* qb = (u16*)(ws + O_QB);
  u16* kb = (u16*)(ws + O_KB);
  u16* vb = (u16*)(ws + O_VB);
  u16* Qw_ = (u16*)(ws + O_QW);
  u16* Kw_ = (u16*)(ws + O_KW);
  u16* Vw_ = (u16*)(ws + O_VW);
  u16* WqT = (u16*)(ws + O_WQT);
  u16* WkT = (u16*)(ws + O_WKT);
  u16* WvT = (u16*)(ws + O_WVT);
  u16* WoT = (u16*)(ws + O_WOT);
  u16* A1T = (u16*)(ws + O_A1T);
  u16* B1T = (u16*)(ws + O_B1T);
  u16* A2T = (u16*)(ws + O_A2T);
  u16* B2T = (u16*)(ws + O_B2T);
  u16* ao = (u16*)(ws + O_AO);
  float* y = (float*)(ws + O_Y);
  float* srcf = (float*)(ws + O_SRCF);
  u16* srcb = (u16*)(ws + O_SRCB);
  u16* ubuf = (u16*)(ws + O_U);
  u16* w2 = (u16*)(ws + O_W2);
  u16* hbuf = (u16*)(ws + O_H);

  cvt4<<<4096, 256, 0, stream>>>(q, qb, 1048576);
  cvt4<<<4096, 256, 0, stream>>>(k, kb, 1048576);
  cvt4<<<4096, 256, 0, stream>>>(v, vb, 1048576);
  transpose_bf16<<<1024, 256, 0, stream>>>(Wq, WqT, 512, 512);
  transpose_bf16<<<1024, 256, 0, stream>>>(Wk, WkT, 512, 512);
  transpose_bf16<<<1024, 256, 0, stream>>>(Wv, WvT, 512, 512);
  transpose_bf16<<<1024, 256, 0, stream>>>(Wo, WoT, 512, 512);
  transpose_bf16<<<128, 256, 0, stream>>>(A1, A1T, 512, 64);
  transpose_bf16<<<512, 256, 0, stream>>>(B1, B1T, 64, 2048);
  transpose_bf16<<<512, 256, 0, stream>>>(A2, A2T, 2048, 64);
  transpose_bf16<<<128, 256, 0, stream>>>(B2, B2T, 64, 512);

  gemm64<2, false><<<dim3(8, 128), 256, 0, stream>>>(qb, WqT, bq, nullptr, Qw_, 8192, 512, 512);
  gemm64<2, false><<<dim3(8, 128), 256, 0, stream>>>(kb, WkT, bk, nullptr, Kw_, 8192, 512, 512);
  gemm64<3, false><<<dim3(8, 128), 256, 0, stream>>>(vb, WvT, bv, nullptr, Vw_, 8192, 512, 512);

  attn_kernel<<<dim3(64, 64), 256, 0, stream>>>(Qw_, Kw_, Vw_, topk, ao);

  gemm64<1, false><<<dim3(8, 128), 256, 0, stream>>>(ao, WoT, bo, q, y, 8192, 512, 512);

  ln_kernel<<<8192, 256, 0, stream>>>(y, g1, be1, srcf, srcb);

  gemm64<0, false><<<dim3(1, 128), 256, 0, stream>>>(srcb, A1T, nullptr, nullptr, ubuf, 8192, 64, 512);
  gemm64<0, true><<<dim3(32, 128), 256, 0, stream>>>(ubuf, B1T, nullptr, nullptr, hbuf, 8192, 2048, 64);
  gemm64<0, false><<<dim3(1, 128), 256, 0, stream>>>(hbuf, A2T, nullptr, nullptr, w2, 8192, 64, 2048);
  gemm64<1, false><<<dim3(8, 128), 256, 0, stream>>>(w2, B2T, nullptr, srcf, y, 8192, 512, 64);

  ln_kernel<<<8192, 256, 0, stream>>>(y, g2, be2, (float*)d_out, nullptr);
}

// Round 3
// 340.150 us; speedup vs baseline: 1.9667x; 1.0566x over previous
//
#include <hip/hip_runtime.h>

typedef unsigned short u16;
typedef unsigned int u32;
using s16x8 = __attribute__((ext_vector_type(8))) short;
using s16x4 = __attribute__((ext_vector_type(4))) short;
using u16x4 = __attribute__((ext_vector_type(4))) unsigned short;
using u32x4 = __attribute__((ext_vector_type(4))) unsigned int;
using f32x4 = __attribute__((ext_vector_type(4))) float;

__device__ __forceinline__ u16 f2bf(float f) {
  unsigned int u = __float_as_uint(f);
  u += 0x7FFFu + ((u >> 16) & 1u);
  return (u16)(u >> 16);
}
__device__ __forceinline__ float bf2f(u16 b) {
  return __uint_as_float(((u32)b) << 16);
}
// monotone 16-bit key from f32 (sign-flip trick, truncated)
__device__ __forceinline__ u32 f2key(float f) {
  u32 u = __float_as_uint(f);
  u32 flip = (u32)((int)u >> 31) | 0x80000000u;
  return (u ^ flip) >> 16;
}
// inverse: 16-bit key -> f32 (truncated value)
__device__ __forceinline__ float key2f(u32 k) {
  u32 fl = 0x8000u | ((((k >> 15) & 1u) - 1u) & 0x7FFFu);
  return __uint_as_float(((k ^ fl) & 0xFFFFu) << 16);
}

// ---------------- fused prep: q/k/v f32->bf16 + 8 weight transposes ----------------
__global__ __launch_bounds__(256) void prep_all(
    const float* __restrict__ q, const float* __restrict__ k, const float* __restrict__ v,
    const float* __restrict__ Wq, const float* __restrict__ Wk, const float* __restrict__ Wv,
    const float* __restrict__ Wo, const float* __restrict__ A1, const float* __restrict__ B1,
    const float* __restrict__ A2, const float* __restrict__ B2,
    u16* __restrict__ qb, u16* __restrict__ kb, u16* __restrict__ vb,
    u16* __restrict__ WqT, u16* __restrict__ WkT, u16* __restrict__ WvT, u16* __restrict__ WoT,
    u16* __restrict__ A1T, u16* __restrict__ B1T, u16* __restrict__ A2T, u16* __restrict__ B2T) {
  int b = blockIdx.x, t = threadIdx.x;
  if (b < 12288) {
    const float* src = b < 4096 ? q : (b < 8192 ? k : v);
    u16* dst = b < 4096 ? qb : (b < 8192 ? kb : vb);
    int i = (b & 4095) * 256 + t;
    float4 f = ((const float4*)src)[i];
    u16x4 o;
    o[0] = f2bf(f.x); o[1] = f2bf(f.y); o[2] = f2bf(f.z); o[3] = f2bf(f.w);
    ((u16x4*)dst)[i] = o;
  } else {
    b -= 12288;
    const float* src; u16* dst; int base, R, C;
    if (b < 1024)      { src = Wq; dst = WqT; base = 0;    R = 512;  C = 512; }
    else if (b < 2048) { src = Wk; dst = WkT; base = 1024; R = 512;  C = 512; }
    else if (b < 3072) { src = Wv; dst = WvT; base = 2048; R = 512;  C = 512; }
    else if (b < 4096) { src = Wo; dst = WoT; base = 3072; R = 512;  C = 512; }
    else if (b < 4224) { src = A1; dst = A1T; base = 4096; R = 512;  C = 64;  }
    else if (b < 4736) { src = B1; dst = B1T; base = 4224; R = 64;   C = 2048;}
    else if (b < 5248) { src = A2; dst = A2T; base = 4736; R = 2048; C = 64;  }
    else               { src = B2; dst = B2T; base = 5248; R = 64;   C = 512; }
    int idx = (b - base) * 256 + t;
    int r = idx / C, c = idx % C;
    dst[(size_t)c * R + r] = f2bf(src[idx]);
  }
}

// ---------------- 128x128-tile bf16 MFMA GEMM ----------------
// C(M,N) = A(M,K) * Bt(N,K)^T. 4 waves, each 64x64 (4x4 fragments), BK=64.
// MODE 0: bf16 out row-major (+RELU). MODE 1: f32 out +bias +resid(f32 or bf16).
// MODE 2: QK scatter out[((n*8+h)*1024+l)*64+d]. MODE 3: V scatter out[((n*8+h)*64+d)*1024+l].
template <int MODE, bool RELU>
__global__ __launch_bounds__(256, 4) void gemm128(const u16* __restrict__ A,
                                                  const u16* __restrict__ Bt,
                                                  const float* __restrict__ bias,
                                                  const float* __restrict__ residf,
                                                  const u16* __restrict__ residb,
                                                  void* __restrict__ outp,
                                                  int M, int N, int K) {
  __shared__ __align__(16) u16 As[128][72];
  __shared__ __align__(16) u16 Bs[128][72];
  const int tid = threadIdx.x;
  const int m0 = blockIdx.y * 128, n0 = blockIdx.x * 128;
  const int lane = tid & 63, wid = tid >> 6;
  const int l16 = lane & 15, hi = lane >> 4;
  const int wr = (wid >> 1) * 64, wc = (wid & 1) * 64;

  f32x4 acc[4][4];
#pragma unroll
  for (int i = 0; i < 4; ++i)
#pragma unroll
    for (int j = 0; j < 4; ++j) acc[i][j] = (f32x4){0.f, 0.f, 0.f, 0.f};

  for (int k0 = 0; k0 < K; k0 += 64) {
    if (k0) __syncthreads();
#pragma unroll
    for (int i = 0; i < 4; ++i) {
      int idx = i * 256 + tid;
      int r = idx >> 3, cc = (idx & 7) * 8;
      *(s16x8*)&As[r][cc] = *(const s16x8*)&A[(size_t)(m0 + r) * K + k0 + cc];
      *(s16x8*)&Bs[r][cc] = *(const s16x8*)&Bt[(size_t)(n0 + r) * K + k0 + cc];
    }
    __syncthreads();
#pragma unroll
    for (int kk = 0; kk < 2; ++kk) {
      const int kb = kk * 32 + hi * 8;
      s16x8 af[4], bf[4];
#pragma unroll
      for (int mf = 0; mf < 4; ++mf) af[mf] = *(const s16x8*)&As[wr + mf * 16 + l16][kb];
#pragma unroll
      for (int nf = 0; nf < 4; ++nf) bf[nf] = *(const s16x8*)&Bs[wc + nf * 16 + l16][kb];
#pragma unroll
      for (int mf = 0; mf < 4; ++mf)
#pragma unroll
        for (int nf = 0; nf < 4; ++nf)
          acc[mf][nf] = __builtin_amdgcn_mfma_f32_16x16x32_bf16(af[mf], bf[nf], acc[mf][nf], 0, 0, 0);
    }
  }

#pragma unroll
  for (int mf = 0; mf < 4; ++mf)
#pragma unroll
    for (int nf = 0; nf < 4; ++nf)
#pragma unroll
      for (int i = 0; i < 4; ++i) {
        int row = m0 + wr + mf * 16 + hi * 4 + i;
        int col = n0 + wc + nf * 16 + l16;
        float val = acc[mf][nf][i];
        if (bias) val += bias[col];
        if (RELU) val = fmaxf(val, 0.f);
        if (MODE == 0) {
          ((u16*)outp)[(size_t)row * N + col] = f2bf(val);
        } else if (MODE == 1) {
          if (residf) val += residf[(size_t)row * N + col];
          else if (residb) val += bf2f(residb[(size_t)row * N + col]);
          ((float*)outp)[(size_t)row * N + col] = val;
        } else if (MODE == 2) {
          int l = row >> 3, n = row & 7, hh = col >> 6, d = col & 63;
          ((u16*)outp)[(((size_t)(n * 8 + hh) * 1024 + l) << 6) + d] = f2bf(val);
        } else {
          int l = row >> 3, n = row & 7, hh = col >> 6, d = col & 63;
          ((u16*)outp)[((size_t)(n * 8 + hh) * 64 + d) * 1024 + l] = f2bf(val);
        }
      }
}

// ---------------- skinny GEMM: N=64, BM=32 (for low-rank FFN legs) ----------------
__global__ __launch_bounds__(256) void gemm32n64(const u16* __restrict__ A,
                                                 const u16* __restrict__ Bt,
                                                 u16* __restrict__ out,
                                                 int M, int K) {
  __shared__ __align__(16) u16 As[32][72];
  __shared__ __align__(16) u16 Bs[64][72];
  const int tid = threadIdx.x;
  const int m0 = blockIdx.y * 32;
  const int lane = tid & 63, wid = tid >> 6;
  const int l16 = lane & 15, hi = lane >> 4;
  const int wm = (wid & 1) * 16, wn = (wid >> 1) * 32;
  f32x4 acc0 = {0.f, 0.f, 0.f, 0.f}, acc1 = {0.f, 0.f, 0.f, 0.f};
  const int rA = tid >> 3, cA = (tid & 7) * 8;
  for (int k0 = 0; k0 < K; k0 += 64) {
    if (k0) __syncthreads();
    *(s16x8*)&As[rA][cA] = *(const s16x8*)&A[(size_t)(m0 + rA) * K + k0 + cA];
#pragma unroll
    for (int i = 0; i < 2; ++i) {
      int idx = i * 256 + tid;
      int r = idx >> 3, cc = (idx & 7) * 8;
      *(s16x8*)&Bs[r][cc] = *(const s16x8*)&Bt[(size_t)r * K + k0 + cc];
    }
    __syncthreads();
#pragma unroll
    for (int kk = 0; kk < 2; ++kk) {
      const int kb = kk * 32 + hi * 8;
      s16x8 a = *(const s16x8*)&As[wm + l16][kb];
      s16x8 b0 = *(const s16x8*)&Bs[wn + l16][kb];
      s16x8 b1 = *(const s16x8*)&Bs[wn + 16 + l16][kb];
      acc0 = __builtin_amdgcn_mfma_f32_16x16x32_bf16(a, b0, acc0, 0, 0, 0);
      acc1 = __builtin_amdgcn_mfma_f32_16x16x32_bf16(a, b1, acc1, 0, 0, 0);
    }
  }
#pragma unroll
  for (int i = 0; i < 4; ++i) {
    int row = m0 + wm + hi * 4 + i;
    out[(size_t)row * 64 + wn + l16] = f2bf(acc0[i]);
    out[(size_t)row * 64 + wn + 16 + l16] = f2bf(acc1[i]);
  }
}

// ---------------- fused attention: QK^T -> top-k mask -> softmax -> PV ----------------
// grid (L/16, 64). Qw/Kw: [nh][l][64] bf16. Vw: [nh][64][1024] bf16 (transposed).
// ao out: [t][d*8+h] bf16, t = l*8+n.
__global__ __launch_bounds__(256, 4) void attn_kernel(const u16* __restrict__ Qw,
                                                      const u16* __restrict__ Kw,
                                                      const u16* __restrict__ Vw,
                                                      const float* __restrict__ topk,
                                                      u16* __restrict__ ao) {
  __shared__ __align__(16) u16 scb[16 * 1024];  // 32KB: keys -> P (bf16), XOR-swizzled
  __shared__ __align__(16) u16 Qt[16][72];
  __shared__ float invs[16];
  const int tid = threadIdx.x, lane = tid & 63, wid = tid >> 6;
  const int l16 = lane & 15, hi = lane >> 4;
  const int mb = blockIdx.x, nh = blockIdx.y;

  const int kkeep = (int)(1024.f / (1.f + __expf(-topk[0])));

  // stage Q tile (16 x 64)
  {
    int r = tid >> 4, dc = (tid & 15) << 2;
    *(s16x4*)&Qt[r][dc] =
        *(const s16x4*)&Qw[((size_t)nh * 1024 + mb * 16 + r) * 64 + dc];
  }
  __syncthreads();

  // ---- Phase A: keys = key(QK^T/8); swapped mfma(K,Q): lane's 4 acc vals are
  // consecutive s for q-row l16 -> packed b64 key writes. Wave w: s in [256w,256w+256).
  {
    const u16* Kb = Kw + (size_t)nh * 1024 * 64;
    s16x8 bq0 = *(const s16x8*)&Qt[l16][hi * 8];
    s16x8 bq1 = *(const s16x8*)&Qt[l16][32 + hi * 8];
    const int s0 = wid * 256;
    const int Xq = (l16 & 7) << 4;
    char* rowq = (char*)scb + l16 * 2048;
#pragma unroll
    for (int nf = 0; nf < 16; ++nf) {
      const int sr = s0 + nf * 16 + l16;
      f32x4 acc = {0.f, 0.f, 0.f, 0.f};
      s16x8 a0 = *(const s16x8*)&Kb[(size_t)sr * 64 + hi * 8];
      s16x8 a1 = *(const s16x8*)&Kb[(size_t)sr * 64 + 32 + hi * 8];
      acc = __builtin_amdgcn_mfma_f32_16x16x32_bf16(a0, bq0, acc, 0, 0, 0);
      acc = __builtin_amdgcn_mfma_f32_16x16x32_bf16(a1, bq1, acc, 0, 0, 0);
      u32 k0 = f2key(acc[0] * 0.125f) | (f2key(acc[1] * 0.125f) << 16);
      u32 k1 = f2key(acc[2] * 0.125f) | (f2key(acc[3] * 0.125f) << 16);
      int boff = (2 * (s0 + nf * 16 + 4 * hi)) ^ Xq;
      *(uint2*)(rowq + boff) = make_uint2(k0, k1);
    }
  }
  __syncthreads();

  // ---- Phase B: per-row top-k (SWAR radix on 15-bit keys) + softmax.
  // 16-lane group hi owns row wid*4+hi; 64 keys/lane. Only dp[32] lives through
  // the radix loop (keys re-read from LDS for the exp pass) -> no spill/reload.
  {
    const int row = wid * 4 + hi;
    const int Xr = (row & 7) << 4;
    char* rowb = (char*)scb + row * 2048;
    u32 dp[32];
#pragma unroll
    for (int c = 0; c < 8; ++c) {
      u32x4 w4 = *(const u32x4*)(rowb + ((16 * l16 + 256 * c) ^ Xr));
#pragma unroll
      for (int t = 0; t < 4; ++t) dp[4 * c + t] = (w4[t] & 0xFFFEFFFEu) >> 1;
    }

    u32 T = 0;
#pragma unroll
    for (int bit = 14; bit >= 0; --bit) {
      u32 cand = T + (1u << bit);
      u32 cc = 0x80008000u - ((cand << 16) | cand);
      u32 acc = 0;
#pragma unroll
      for (int i = 0; i < 32; ++i) acc += ((dp[i] + cc) >> 15) & 0x00010001u;
      int cnt = (int)((acc & 0xFFFFu) + (acc >> 16));
      cnt += __shfl_xor(cnt, 1); cnt += __shfl_xor(cnt, 2);
      cnt += __shfl_xor(cnt, 4); cnt += __shfl_xor(cnt, 8);
      if (cnt >= kkeep) T = cand;
    }

    // max (15-bit) -- softmax is shift-invariant, truncated max is exact enough
    u32 mx = 0;
#pragma unroll
    for (int i = 0; i < 32; ++i) mx = max(mx, max(dp[i] << 16, dp[i] & 0xFFFF0000u));
    mx = max(mx, (u32)__shfl_xor((int)mx, 1));
    mx = max(mx, (u32)__shfl_xor((int)mx, 2));
    mx = max(mx, (u32)__shfl_xor((int)mx, 4));
    mx = max(mx, (u32)__shfl_xor((int)mx, 8));
    const float mval = key2f((mx >> 16) << 1);
    const u32 T2 = T << 1;  // keep iff key16 >= T2

    float sum = 0.f;
#pragma unroll
    for (int c = 0; c < 8; ++c) {
      char* p = rowb + ((16 * l16 + 256 * c) ^ Xr);
      u32x4 w4 = *(const u32x4*)p;  // original 16-bit keys
      u32 outw[4];
#pragma unroll
      for (int t = 0; t < 4; ++t) {
        u32 w = w4[t];
        u32 klo = w & 0xFFFFu, khi = w >> 16;
        float vlo = key2f(klo), vhi = key2f(khi);
        float elo = (klo >= T2) ? __expf(vlo - mval) : 0.f;
        float ehi = (khi >= T2) ? __expf(vhi - mval) : 0.f;
        sum += elo + ehi;
        outw[t] = (u32)f2bf(elo) | ((u32)f2bf(ehi) << 16);
      }
      *(u32x4*)p = *(u32x4*)outw;
    }
    sum += __shfl_xor(sum, 1); sum += __shfl_xor(sum, 2);
    sum += __shfl_xor(sum, 4); sum += __shfl_xor(sum, 8);
    if (l16 == 0) invs[row] = __builtin_amdgcn_rcpf(sum);
  }
  __syncthreads();

  // ---- Phase C: out = (P @ V) * inv, wave w owns d in [16w, 16w+16) ----
  {
    const u16* Vb = Vw + (size_t)nh * 64 * 1024;
    const int d0 = wid * 16;
    f32x4 oacc0 = {0.f, 0.f, 0.f, 0.f};
    f32x4 oacc1 = {0.f, 0.f, 0.f, 0.f};
    const char* Pbase = (const char*)scb + l16 * 2048;
    const int Xp = (l16 & 7) << 4;
#pragma unroll
    for (int ks = 0; ks < 32; ks += 2) {
      int kb0 = (ks * 64 + hi * 16) ^ Xp;
      int kb1 = ((ks + 1) * 64 + hi * 16) ^ Xp;
      s16x8 a0 = *(const s16x8*)(Pbase + kb0);
      s16x8 a1 = *(const s16x8*)(Pbase + kb1);
      s16x8 b0 = *(const s16x8*)&Vb[(size_t)(d0 + l16) * 1024 + ks * 32 + hi * 8];
      s16x8 b1 = *(const s16x8*)&Vb[(size_t)(d0 + l16) * 1024 + (ks + 1) * 32 + hi * 8];
      oacc0 = __builtin_amdgcn_mfma_f32_16x16x32_bf16(a0, b0, oacc0, 0, 0, 0);
      oacc1 = __builtin_amdgcn_mfma_f32_16x16x32_bf16(a1, b1, oacc1, 0, 0, 0);
    }
    const int n = nh >> 3, hh = nh & 7;
#pragma unroll
    for (int i = 0; i < 4; ++i) {
      int l = mb * 16 + hi * 4 + i;
      int d = d0 + l16;
      float v = (oacc0[i] + oacc1[i]) * invs[hi * 4 + i];
      ao[(size_t)(l * 8 + n) * 512 + d * 8 + hh] = f2bf(v);
    }
  }
}

// ---------------- LayerNorm over rows of 512 ----------------
__global__ __launch_bounds__(256) void ln_kernel(const float* __restrict__ x,
                                                 const float* __restrict__ g,
                                                 const float* __restrict__ b,
                                                 float* __restrict__ of,
                                                 u16* __restrict__ ob) {
  __shared__ float red[8];
  const int t = blockIdx.x, tid = threadIdx.x;
  const int lane = tid & 63, wid = tid >> 6;
  const float* xr = x + (size_t)t * 512;
  float x0 = xr[tid], x1 = xr[tid + 256];
  float s = x0 + x1;
#pragma unroll
  for (int off = 32; off; off >>= 1) s += __shfl_xor(s, off);
  if (lane == 0) red[wid] = s;
  __syncthreads();
  const float mean = (red[0] + red[1] + red[2] + red[3]) * (1.f / 512.f);
  const float d0 = x0 - mean, d1 = x1 - mean;
  float q2 = d0 * d0 + d1 * d1;
#pragma unroll
  for (int off = 32; off; off >>= 1) q2 += __shfl_xor(q2, off);
  if (lane == 0) red[4 + wid] = q2;
  __syncthreads();
  const float var = (red[4] + red[5] + red[6] + red[7]) * (1.f / 512.f);
  const float inv = rsqrtf(var + 1e-5f);
  const float y0 = d0 * inv * g[tid] + b[tid];
  const float y1 = d1 * inv * g[tid + 256] + b[tid + 256];
  if (of) {
    of[(size_t)t * 512 + tid] = y0;
    of[(size_t)t * 512 + tid + 256] = y1;
  }
  if (ob) {
    ob[(size_t)t * 512 + tid] = f2bf(y0);
    ob[(size_t)t * 512 + tid + 256] = f2bf(y1);
  }
}

// ---------------- host launch ----------------
extern "C" void kernel_launch(void* const* d_in, const int* in_sizes, int n_in,
                              void* d_out, int out_size, void* d_ws, size_t ws_size,
                              hipStream_t stream) {
  const float* q = (const float*)d_in[0];
  const float* k = (const float*)d_in[1];
  const float* v = (const float*)d_in[2];
  const float* Wq = (const float*)d_in[3];
  const float* bq = (const float*)d_in[4];
  const float* Wk = (const float*)d_in[5];
  const float* bk = (const float*)d_in[6];
  const float* Wv = (const float*)d_in[7];
  const float* bv = (const float*)d_in[8];
  const float* Wo = (const float*)d_in[9];
  const float* bo = (const float*)d_in[10];
  const float* topk = (const float*)d_in[11];
  const float* A1 = (const float*)d_in[12];
  const float* B1 = (const float*)d_in[13];
  const float* A2 = (const float*)d_in[14];
  const float* B2 = (const float*)d_in[15];
  const float* g1 = (const float*)d_in[16];
  const float* be1 = (const float*)d_in[17];
  const float* g2 = (const float*)d_in[18];
  const float* be2 = (const float*)d_in[19];

  char* ws = (char*)d_ws;
  constexpr size_t SZ_TOK_BF = (size_t)8192 * 512 * 2;
  constexpr size_t SZ_W_BF = (size_t)512 * 512 * 2;
  constexpr size_t O_QB = 0;
  constexpr size_t O_KB = O_QB + SZ_TOK_BF;
  constexpr size_t O_VB = O_KB + SZ_TOK_BF;
  constexpr size_t O_QW = O_VB + SZ_TOK_BF;
  constexpr size_t O_KW = O_QW + SZ_TOK_BF;
  constexpr size_t O_VW = O_KW + SZ_TOK_BF;
  constexpr size_t O_WQT = O_VW + SZ_TOK_BF;
  constexpr size_t O_WKT = O_WQT + SZ_W_BF;
  constexpr size_t O_WVT = O_WKT + SZ_W_BF;
  constexpr size_t O_WOT = O_WVT + SZ_W_BF;
  constexpr size_t O_A1T = O_WOT + SZ_W_BF;
  constexpr size_t O_B1T = O_A1T + 65536;
  constexpr size_t O_A2T = O_B1T + 262144;
  constexpr size_t O_B2T = O_A2T + 262144;
  constexpr size_t O_AO = O_B2T + 65536;
  constexpr size_t O_Y = O_AO + SZ_TOK_BF;
  constexpr size_t O_SRCB = O_Y + (size_t)8192 * 512 * 4;
  constexpr size_t O_U = O_SRCB + SZ_TOK_BF;
  constexpr size_t O_W2 = O_U + (size_t)8192 * 64 * 2;
  constexpr size_t O_H = 0;  // overlays qb/kb/vb/Qw (all dead by FFN time)

  u16* qb = (u16*)(ws + O_QB);
  u16* kb = (u16*)(ws + O_KB);
  u16* vb = (u16*)(ws + O_VB);
  u16* Qw_ = (u16*)(ws + O_QW);
  u16* Kw_ = (u16*)(ws + O_KW);
  u16* Vw_ = (u16*)(ws + O_VW);
  u16* WqT = (u16*)(ws + O_WQT);
  u16* WkT = (u16*)(ws + O_WKT);
  u16* WvT = (u16*)(ws + O_WVT);
  u16* WoT = (u16*)(ws + O_WOT);
  u16* A1T = (u16*)(ws + O_A1T);
  u16* B1T = (u16*)(ws + O_B1T);
  u16* A2T = (u16*)(ws + O_A2T);
  u16* B2T = (u16*)(ws + O_B2T);
  u16* ao = (u16*)(ws + O_AO);
  float* y = (float*)(ws + O_Y);
  u16* srcb = (u16*)(ws + O_SRCB);
  u16* ubuf = (u16*)(ws + O_U);
  u16* w2 = (u16*)(ws + O_W2);
  u16* hbuf = (u16*)(ws + O_H);

  // 1) all input conversions/transposes in one launch
  prep_all<<<17664, 256, 0, stream>>>(q, k, v, Wq, Wk, Wv, Wo, A1, B1, A2, B2,
                                      qb, kb, vb, WqT, WkT, WvT, WoT, A1T, B1T, A2T, B2T);

  // 2) QKV projections with head-scatter epilogues (128x128 tiles)
  gemm128<2, false><<<dim3(4, 64), 256, 0, stream>>>(qb, WqT, bq, nullptr, nullptr, Qw_, 8192, 512, 512);
  gemm128<2, false><<<dim3(4, 64), 256, 0, stream>>>(kb, WkT, bk, nullptr, nullptr, Kw_, 8192, 512, 512);
  gemm128<3, false><<<dim3(4, 64), 256, 0, stream>>>(vb, WvT, bv, nullptr, nullptr, Vw_, 8192, 512, 512);

  // 3) fused attention
  attn_kernel<<<dim3(64, 64), 256, 0, stream>>>(Qw_, Kw_, Vw_, topk, ao);

  // 4) Wo projection + bias + residual(q, f32) -> y
  gemm128<1, false><<<dim3(4, 64), 256, 0, stream>>>(ao, WoT, bo, q, nullptr, y, 8192, 512, 512);

  // 5) LN1 -> srcb (bf16 only; residual for final GEMM also read as bf16)
  ln_kernel<<<8192, 256, 0, stream>>>(y, g1, be1, nullptr, srcb);

  // 6) FFN: u = src@A1 ; h = relu(u@B1) ; w2 = h@A2 ; y = w2@B2 + src
  gemm32n64<<<dim3(1, 256), 256, 0, stream>>>(srcb, A1T, ubuf, 8192, 512);
  gemm128<0, true><<<dim3(16, 64), 256, 0, stream>>>(ubuf, B1T, nullptr, nullptr, nullptr, hbuf, 8192, 2048, 64);
  gemm32n64<<<dim3(1, 256), 256, 0, stream>>>(hbuf, A2T, w2, 8192, 2048);
  gemm128<1, false><<<dim3(4, 64), 256, 0, stream>>>(w2, B2T, nullptr, nullptr, srcb, y, 8192, 512, 64);

  // 7) LN2 -> d_out (f32)
  ln_kernel<<<8192, 256, 0, stream>>>(y, g2, be2, (float*)d_out, nullptr);
}

// Round 4
// 281.957 us; speedup vs baseline: 2.3726x; 1.2064x over previous
//
#include <hip/hip_runtime.h>

typedef unsigned short u16;
typedef unsigned int u32;
using s16x8 = __attribute__((ext_vector_type(8))) short;
using s16x4 = __attribute__((ext_vector_type(4))) short;
using u16x4 = __attribute__((ext_vector_type(4))) unsigned short;
using u32x4 = __attribute__((ext_vector_type(4))) unsigned int;
using f32x4 = __attribute__((ext_vector_type(4))) float;

__device__ __forceinline__ u16 f2bf(float f) {
  unsigned int u = __float_as_uint(f);
  u += 0x7FFFu + ((u >> 16) & 1u);
  return (u16)(u >> 16);
}
__device__ __forceinline__ float bf2f(u16 b) {
  return __uint_as_float(((u32)b) << 16);
}
// monotone 16-bit key from f32 (sign-flip trick, truncated)
__device__ __forceinline__ u32 f2key(float f) {
  u32 u = __float_as_uint(f);
  u32 flip = (u32)((int)u >> 31) | 0x80000000u;
  return (u ^ flip) >> 16;
}
// inverse: 16-bit key -> f32 (truncated value)
__device__ __forceinline__ float key2f(u32 k) {
  u32 fl = 0x8000u | ((((k >> 15) & 1u) - 1u) & 0x7FFFu);
  return __uint_as_float(((k ^ fl) & 0xFFFFu) << 16);
}

// ---------------- fused prep: q/k/v f32->bf16 + 8 weight transposes ----------------
__global__ __launch_bounds__(256) void prep_all(
    const float* __restrict__ q, const float* __restrict__ k, const float* __restrict__ v,
    const float* __restrict__ Wq, const float* __restrict__ Wk, const float* __restrict__ Wv,
    const float* __restrict__ Wo, const float* __restrict__ A1, const float* __restrict__ B1,
    const float* __restrict__ A2, const float* __restrict__ B2,
    u16* __restrict__ qb, u16* __restrict__ kb, u16* __restrict__ vb,
    u16* __restrict__ WqT, u16* __restrict__ WkT, u16* __restrict__ WvT, u16* __restrict__ WoT,
    u16* __restrict__ A1T, u16* __restrict__ B1T, u16* __restrict__ A2T, u16* __restrict__ B2T) {
  int b = blockIdx.x, t = threadIdx.x;
  if (b < 12288) {
    const float* src = b < 4096 ? q : (b < 8192 ? k : v);
    u16* dst = b < 4096 ? qb : (b < 8192 ? kb : vb);
    int i = (b & 4095) * 256 + t;
    float4 f = ((const float4*)src)[i];
    u16x4 o;
    o[0] = f2bf(f.x); o[1] = f2bf(f.y); o[2] = f2bf(f.z); o[3] = f2bf(f.w);
    ((u16x4*)dst)[i] = o;
  } else {
    b -= 12288;
    const float* src; u16* dst; int base, R, C;
    if (b < 1024)      { src = Wq; dst = WqT; base = 0;    R = 512;  C = 512; }
    else if (b < 2048) { src = Wk; dst = WkT; base = 1024; R = 512;  C = 512; }
    else if (b < 3072) { src = Wv; dst = WvT; base = 2048; R = 512;  C = 512; }
    else if (b < 4096) { src = Wo; dst = WoT; base = 3072; R = 512;  C = 512; }
    else if (b < 4224) { src = A1; dst = A1T; base = 4096; R = 512;  C = 64;  }
    else if (b < 4736) { src = B1; dst = B1T; base = 4224; R = 64;   C = 2048;}
    else if (b < 5248) { src = A2; dst = A2T; base = 4736; R = 2048; C = 64;  }
    else               { src = B2; dst = B2T; base = 5248; R = 64;   C = 512; }
    int idx = (b - base) * 256 + t;
    int r = idx / C, c = idx % C;
    dst[(size_t)c * R + r] = f2bf(src[idx]);
  }
}

// ---------------- fused QKV projection: 128x128 tiles, grid (4,64,3) ----------------
// z=0: Q (scaled by 0.125, scatter [nh][l][d]); z=1: K (scatter [nh][l][d]);
// z=2: V (scatter [nh][d][l]).
__global__ __launch_bounds__(256, 4) void qkv_fused(
    const u16* __restrict__ qb, const u16* __restrict__ kb, const u16* __restrict__ vb,
    const u16* __restrict__ WqT, const u16* __restrict__ WkT, const u16* __restrict__ WvT,
    const float* __restrict__ bq, const float* __restrict__ bk, const float* __restrict__ bv,
    u16* __restrict__ Qw, u16* __restrict__ Kw, u16* __restrict__ Vw) {
  __shared__ __align__(16) u16 As[128][72];
  __shared__ __align__(16) u16 Bs[128][72];
  const int z = blockIdx.z;
  const u16* A = z == 0 ? qb : (z == 1 ? kb : vb);
  const u16* Bt = z == 0 ? WqT : (z == 1 ? WkT : WvT);
  const float* bias = z == 0 ? bq : (z == 1 ? bk : bv);
  u16* outp = z == 0 ? Qw : (z == 1 ? Kw : Vw);

  const int tid = threadIdx.x;
  const int m0 = blockIdx.y * 128, n0 = blockIdx.x * 128;
  const int lane = tid & 63, wid = tid >> 6;
  const int l16 = lane & 15, hi = lane >> 4;
  const int wr = (wid >> 1) * 64, wc = (wid & 1) * 64;

  f32x4 acc[4][4];
#pragma unroll
  for (int i = 0; i < 4; ++i)
#pragma unroll
    for (int j = 0; j < 4; ++j) acc[i][j] = (f32x4){0.f, 0.f, 0.f, 0.f};

  for (int k0 = 0; k0 < 512; k0 += 64) {
    if (k0) __syncthreads();
#pragma unroll
    for (int i = 0; i < 4; ++i) {
      int idx = i * 256 + tid;
      int r = idx >> 3, cc = (idx & 7) * 8;
      *(s16x8*)&As[r][cc] = *(const s16x8*)&A[(size_t)(m0 + r) * 512 + k0 + cc];
      *(s16x8*)&Bs[r][cc] = *(const s16x8*)&Bt[(size_t)(n0 + r) * 512 + k0 + cc];
    }
    __syncthreads();
#pragma unroll
    for (int kk = 0; kk < 2; ++kk) {
      const int kb_ = kk * 32 + hi * 8;
      s16x8 af[4], bf[4];
#pragma unroll
      for (int mf = 0; mf < 4; ++mf) af[mf] = *(const s16x8*)&As[wr + mf * 16 + l16][kb_];
#pragma unroll
      for (int nf = 0; nf < 4; ++nf) bf[nf] = *(const s16x8*)&Bs[wc + nf * 16 + l16][kb_];
#pragma unroll
      for (int mf = 0; mf < 4; ++mf)
#pragma unroll
        for (int nf = 0; nf < 4; ++nf)
          acc[mf][nf] = __builtin_amdgcn_mfma_f32_16x16x32_bf16(af[mf], bf[nf], acc[mf][nf], 0, 0, 0);
    }
  }

#pragma unroll
  for (int mf = 0; mf < 4; ++mf)
#pragma unroll
    for (int nf = 0; nf < 4; ++nf)
#pragma unroll
      for (int i = 0; i < 4; ++i) {
        int row = m0 + wr + mf * 16 + hi * 4 + i;
        int col = n0 + wc + nf * 16 + l16;
        float val = acc[mf][nf][i] + bias[col];
        if (z == 0) val *= 0.125f;  // fold 1/sqrt(Dh) into Q (exact in bf16)
        int l = row >> 3, n = row & 7, hh = col >> 6, d = col & 63;
        if (z < 2)
          outp[(((size_t)(n * 8 + hh) * 1024 + l) << 6) + d] = f2bf(val);
        else
          outp[((size_t)(n * 8 + hh) * 64 + d) * 1024 + l] = f2bf(val);
      }
}

// ---------------- fused attention: QK^T -> top-k mask -> softmax -> PV ----------------
// grid (L/32, 64), 512 threads (8 waves). Qw (pre-scaled)/Kw: [nh][l][64]. Vw: [nh][64][1024].
// ao out: [t][d*8+h] bf16, t = l*8+n.
__global__ __launch_bounds__(512, 4) void attn_kernel(const u16* __restrict__ Qw,
                                                      const u16* __restrict__ Kw,
                                                      const u16* __restrict__ Vw,
                                                      const float* __restrict__ topk,
                                                      u16* __restrict__ ao) {
  __shared__ __align__(16) u16 scb[32 * 1024];  // 64KB: keys -> P (bf16), XOR-swizzled
  __shared__ __align__(16) u16 Qt[32][72];
  __shared__ float invs[32];
  const int tid = threadIdx.x, lane = tid & 63, wid = tid >> 6;
  const int l16 = lane & 15, hi = lane >> 4;
  const int mb = blockIdx.x, nh = blockIdx.y;

  const int kkeep = (int)(1024.f / (1.f + __expf(-topk[0])));

  // stage Q tile (32 x 64)
  {
    int r = tid >> 4, dc = (tid & 15) << 2;
    *(s16x4*)&Qt[r][dc] =
        *(const s16x4*)&Qw[((size_t)nh * 1024 + mb * 32 + r) * 64 + dc];
  }
  __syncthreads();

  // ---- Phase A: keys = key(QK^T) (Q pre-scaled). swapped mfma(K,Q): lane's 4 acc
  // vals are consecutive s for one q-row. Wave w covers s in [128w, 128w+128).
  {
    const u16* Kb = Kw + (size_t)nh * 1024 * 64;
    s16x8 bq0[2], bq1[2];
#pragma unroll
    for (int qh = 0; qh < 2; ++qh) {
      bq0[qh] = *(const s16x8*)&Qt[qh * 16 + l16][hi * 8];
      bq1[qh] = *(const s16x8*)&Qt[qh * 16 + l16][32 + hi * 8];
    }
    const int s0 = wid * 128;
#pragma unroll
    for (int nf = 0; nf < 8; ++nf) {
      const int sr = s0 + nf * 16 + l16;
      s16x8 a0 = *(const s16x8*)&Kb[(size_t)sr * 64 + hi * 8];
      s16x8 a1 = *(const s16x8*)&Kb[(size_t)sr * 64 + 32 + hi * 8];
#pragma unroll
      for (int qh = 0; qh < 2; ++qh) {
        f32x4 acc = {0.f, 0.f, 0.f, 0.f};
        acc = __builtin_amdgcn_mfma_f32_16x16x32_bf16(a0, bq0[qh], acc, 0, 0, 0);
        acc = __builtin_amdgcn_mfma_f32_16x16x32_bf16(a1, bq1[qh], acc, 0, 0, 0);
        // acc[i] = score for (q = qh*16 + l16, s = s0 + 16*nf + 4*hi + i)
        const int row_q = qh * 16 + l16;
        u32 k0 = f2key(acc[0]) | (f2key(acc[1]) << 16);
        u32 k1 = f2key(acc[2]) | (f2key(acc[3]) << 16);
        char* rowq = (char*)scb + row_q * 2048;
        int boff = (2 * (s0 + nf * 16 + 4 * hi)) ^ ((row_q & 7) << 4);
        *(uint2*)(rowq + boff) = make_uint2(k0, k1);
      }
    }
  }
  __syncthreads();

  // ---- Phase B: per-row top-k (SWAR radix on 15-bit keys) + softmax.
  // 16-lane group hi of wave wid owns row wid*4+hi; 64 keys/lane.
  {
    const int row = wid * 4 + hi;
    const int Xr = (row & 7) << 4;
    char* rowb = (char*)scb + row * 2048;
    u32 dp[32];
#pragma unroll
    for (int c = 0; c < 8; ++c) {
      u32x4 w4 = *(const u32x4*)(rowb + ((16 * l16 + 256 * c) ^ Xr));
#pragma unroll
      for (int t = 0; t < 4; ++t) dp[4 * c + t] = (w4[t] & 0xFFFEFFFEu) >> 1;
    }

    u32 T = 0;
#pragma unroll
    for (int bit = 14; bit >= 0; --bit) {
      u32 cand = T + (1u << bit);
      u32 cc = 0x80008000u - ((cand << 16) | cand);
      u32 acc = 0;
#pragma unroll
      for (int i = 0; i < 32; ++i) acc += ((dp[i] + cc) >> 15) & 0x00010001u;
      int cnt = (int)((acc & 0xFFFFu) + (acc >> 16));
      cnt += __shfl_xor(cnt, 1); cnt += __shfl_xor(cnt, 2);
      cnt += __shfl_xor(cnt, 4); cnt += __shfl_xor(cnt, 8);
      if (cnt >= kkeep) T = cand;
    }

    // max (15-bit prefix) -- softmax is shift-invariant, truncation harmless
    u32 mx = 0;
#pragma unroll
    for (int i = 0; i < 32; ++i) mx = max(mx, max(dp[i] << 16, dp[i] & 0xFFFF0000u));
    mx = max(mx, (u32)__shfl_xor((int)mx, 1));
    mx = max(mx, (u32)__shfl_xor((int)mx, 2));
    mx = max(mx, (u32)__shfl_xor((int)mx, 4));
    mx = max(mx, (u32)__shfl_xor((int)mx, 8));
    const float mval = key2f((mx >> 16) << 1);
    const u32 T2 = T << 1;  // keep iff key16 >= T2

    float sum = 0.f;
#pragma unroll
    for (int c = 0; c < 8; ++c) {
      char* p = rowb + ((16 * l16 + 256 * c) ^ Xr);
      u32x4 w4 = *(const u32x4*)p;  // original 16-bit keys
      u32 outw[4];
#pragma unroll
      for (int t = 0; t < 4; ++t) {
        u32 w = w4[t];
        u32 tlo = w << 16;
        u32 thi = w & 0xFFFF0000u;
        u32 flo = ((int)tlo < 0) ? 0x80000000u : 0xFFFF0000u;
        u32 fhi = ((int)thi < 0) ? 0x80000000u : 0xFFFF0000u;
        float vlo = __uint_as_float(tlo ^ flo);
        float vhi = __uint_as_float(thi ^ fhi);
        float elo = ((w & 0xFFFFu) >= T2) ? __expf(vlo - mval) : 0.f;
        float ehi = ((w >> 16) >= T2) ? __expf(vhi - mval) : 0.f;
        sum += elo + ehi;
        u32 pk;
        asm("v_cvt_pk_bf16_f32 %0, %1, %2" : "=v"(pk) : "v"(elo), "v"(ehi));
        outw[t] = pk;
      }
      *(u32x4*)p = *(u32x4*)outw;
    }
    sum += __shfl_xor(sum, 1); sum += __shfl_xor(sum, 2);
    sum += __shfl_xor(sum, 4); sum += __shfl_xor(sum, 8);
    if (l16 == 0) invs[row] = __builtin_amdgcn_rcpf(sum);
  }
  __syncthreads();

  // ---- Phase C: out = (P @ V) * inv. wave w: rows [16*(w>>2)..+16), d [16*(w&3)..+16) ----
  {
    const u16* Vb = Vw + (size_t)nh * 64 * 1024;
    const int rh = wid >> 2, d0 = (wid & 3) * 16;
    f32x4 oacc0 = {0.f, 0.f, 0.f, 0.f};
    f32x4 oacc1 = {0.f, 0.f, 0.f, 0.f};
    const char* Pbase = (const char*)scb + (rh * 16 + l16) * 2048;
    const int Xp = (l16 & 7) << 4;
#pragma unroll
    for (int ks = 0; ks < 32; ks += 2) {
      int kb0 = (ks * 64 + hi * 16) ^ Xp;
      int kb1 = ((ks + 1) * 64 + hi * 16) ^ Xp;
      s16x8 a0 = *(const s16x8*)(Pbase + kb0);
      s16x8 a1 = *(const s16x8*)(Pbase + kb1);
      s16x8 b0 = *(const s16x8*)&Vb[(size_t)(d0 + l16) * 1024 + ks * 32 + hi * 8];
      s16x8 b1 = *(const s16x8*)&Vb[(size_t)(d0 + l16) * 1024 + (ks + 1) * 32 + hi * 8];
      oacc0 = __builtin_amdgcn_mfma_f32_16x16x32_bf16(a0, b0, oacc0, 0, 0, 0);
      oacc1 = __builtin_amdgcn_mfma_f32_16x16x32_bf16(a1, b1, oacc1, 0, 0, 0);
    }
    const int n = nh >> 3, hh = nh & 7;
#pragma unroll
    for (int i = 0; i < 4; ++i) {
      int l = mb * 32 + rh * 16 + hi * 4 + i;
      int d = d0 + l16;
      float vv = (oacc0[i] + oacc1[i]) * invs[rh * 16 + hi * 4 + i];
      ao[(size_t)(l * 8 + n) * 512 + d * 8 + hh] = f2bf(vv);
    }
  }
}

// ---------------- GEMM (BM=16, N=512, B direct from L2) + bias + resid + LayerNorm ----------------
// FIRST: out = LN1(ao@WoT + bo + q) -> srcb (bf16), K=512, residf=q
// else : out = LN2(w2@B2T + srcb)  -> d_out (f32), K=64, residb=srcb
template <bool FIRST>
__global__ __launch_bounds__(256, 2) void gemm_ln(const u16* __restrict__ A,
                                                  const u16* __restrict__ Bt,
                                                  const float* __restrict__ bias,
                                                  const float* __restrict__ residf,
                                                  const u16* __restrict__ residb,
                                                  const float* __restrict__ g,
                                                  const float* __restrict__ be,
                                                  float* __restrict__ outf,
                                                  u16* __restrict__ outb) {
  constexpr int K = FIRST ? 512 : 64;
  __shared__ __align__(16) u16 As[16][72];
  __shared__ float red_s[4][16];
  __shared__ float red_q[4][16];
  const int tid = threadIdx.x;
  const int lane = tid & 63, wid = tid >> 6;
  const int l16 = lane & 15, hi = lane >> 4;
  const int m0 = blockIdx.x * 16;
  const int wc = wid * 128;

  f32x4 acc[8];
#pragma unroll
  for (int nf = 0; nf < 8; ++nf) acc[nf] = (f32x4){0.f, 0.f, 0.f, 0.f};

  for (int k0 = 0; k0 < K; k0 += 64) {
    if (k0) __syncthreads();
    {
      int r = tid >> 4, c = (tid & 15) << 2;
      *(s16x4*)&As[r][c] = *(const s16x4*)&A[(size_t)(m0 + r) * K + k0 + c];
    }
    __syncthreads();
#pragma unroll
    for (int kk = 0; kk < 2; ++kk) {
      const int kb_ = kk * 32 + hi * 8;
      s16x8 a = *(const s16x8*)&As[l16][kb_];
#pragma unroll
      for (int nf = 0; nf < 8; ++nf) {
        s16x8 b = *(const s16x8*)&Bt[(size_t)(wc + nf * 16 + l16) * K + k0 + kb_];
        acc[nf] = __builtin_amdgcn_mfma_f32_16x16x32_bf16(a, b, acc[nf], 0, 0, 0);
      }
    }
  }

  // epilogue: bias + residual, then LN over the 512-wide row (rows = hi*4+i)
#pragma unroll
  for (int nf = 0; nf < 8; ++nf) {
    int col = wc + nf * 16 + l16;
#pragma unroll
    for (int i = 0; i < 4; ++i) {
      float v = acc[nf][i];
      int row = m0 + hi * 4 + i;
      if (FIRST) v += bias[col] + residf[(size_t)row * 512 + col];
      else v += bf2f(residb[(size_t)row * 512 + col]);
      acc[nf][i] = v;
    }
  }
  float s[4] = {0.f, 0.f, 0.f, 0.f}, q2[4] = {0.f, 0.f, 0.f, 0.f};
#pragma unroll
  for (int nf = 0; nf < 8; ++nf)
#pragma unroll
    for (int i = 0; i < 4; ++i) {
      s[i] += acc[nf][i];
      q2[i] += acc[nf][i] * acc[nf][i];
    }
#pragma unroll
  for (int i = 0; i < 4; ++i) {
#pragma unroll
    for (int off = 1; off < 16; off <<= 1) {
      s[i] += __shfl_xor(s[i], off);
      q2[i] += __shfl_xor(q2[i], off);
    }
  }
  if (l16 == 0) {
#pragma unroll
    for (int i = 0; i < 4; ++i) {
      red_s[wid][hi * 4 + i] = s[i];
      red_q[wid][hi * 4 + i] = q2[i];
    }
  }
  __syncthreads();
  float mean[4], rstd[4];
#pragma unroll
  for (int i = 0; i < 4; ++i) {
    int r = hi * 4 + i;
    float ms = red_s[0][r] + red_s[1][r] + red_s[2][r] + red_s[3][r];
    float mq = red_q[0][r] + red_q[1][r] + red_q[2][r] + red_q[3][r];
    mean[i] = ms * (1.f / 512.f);
    float var = mq * (1.f / 512.f) - mean[i] * mean[i];
    rstd[i] = rsqrtf(var + 1e-5f);
  }
#pragma unroll
  for (int nf = 0; nf < 8; ++nf) {
    int col = wc + nf * 16 + l16;
    float gv = g[col], bev = be[col];
#pragma unroll
    for (int i = 0; i < 4; ++i) {
      int row = m0 + hi * 4 + i;
      float y = (acc[nf][i] - mean[i]) * rstd[i] * gv + bev;
      if (FIRST) outb[(size_t)row * 512 + col] = f2bf(y);
      else outf[(size_t)row * 512 + col] = y;
    }
  }
}

// ---------------- fused low-rank FFN: w2 = relu(src@A1 @ B1) @ A2 ----------------
// grid(256), 256 threads, BM=32. h (8192x2048) never touches global memory.
__global__ __launch_bounds__(256, 4) void ffn3(const u16* __restrict__ srcb,
                                               const u16* __restrict__ A1T,
                                               const u16* __restrict__ B1T,
                                               const u16* __restrict__ A2T,
                                               u16* __restrict__ w2) {
  __shared__ __align__(16) u16 As[32][72];
  __shared__ __align__(16) u16 Bs[64][72];
  __shared__ __align__(16) u16 Us[32][72];
  __shared__ __align__(16) u16 B1s[64][72];
  __shared__ __align__(16) u16 A2s[64][72];
  __shared__ __align__(16) u16 Hs[32][72];
  const int tid = threadIdx.x;
  const int lane = tid & 63, wid = tid >> 6;
  const int l16 = lane & 15, hi = lane >> 4;
  const int m0 = blockIdx.x * 32;
  const int wm = (wid & 1) * 16, wn = (wid >> 1) * 32;

  // stage 1: u(32x64) = srcb_tile @ A1T^T
  f32x4 accu[2];
  accu[0] = (f32x4){0.f, 0.f, 0.f, 0.f};
  accu[1] = (f32x4){0.f, 0.f, 0.f, 0.f};
  for (int k0 = 0; k0 < 512; k0 += 64) {
    if (k0) __syncthreads();
    {
      int r = tid >> 3, c = (tid & 7) << 3;
      *(s16x8*)&As[r][c] = *(const s16x8*)&srcb[(size_t)(m0 + r) * 512 + k0 + c];
    }
#pragma unroll
    for (int i = 0; i < 2; ++i) {
      int idx = i * 256 + tid;
      int r = idx >> 3, c = (idx & 7) << 3;
      *(s16x8*)&Bs[r][c] = *(const s16x8*)&A1T[(size_t)r * 512 + k0 + c];
    }
    __syncthreads();
#pragma unroll
    for (int kk = 0; kk < 2; ++kk) {
      const int kb_ = kk * 32 + hi * 8;
      s16x8 a = *(const s16x8*)&As[wm + l16][kb_];
#pragma unroll
      for (int j = 0; j < 2; ++j) {
        s16x8 b = *(const s16x8*)&Bs[wn + j * 16 + l16][kb_];
        accu[j] = __builtin_amdgcn_mfma_f32_16x16x32_bf16(a, b, accu[j], 0, 0, 0);
      }
    }
  }
  __syncthreads();
#pragma unroll
  for (int j = 0; j < 2; ++j)
#pragma unroll
    for (int i = 0; i < 4; ++i)
      Us[wm + hi * 4 + i][wn + j * 16 + l16] = f2bf(accu[j][i]);

  // stage 2: loop 64-wide j-chunks: h = relu(u@B1c); w2 += h@A2c
  f32x4 w2a[2];
  w2a[0] = (f32x4){0.f, 0.f, 0.f, 0.f};
  w2a[1] = (f32x4){0.f, 0.f, 0.f, 0.f};
  for (int jc = 0; jc < 32; ++jc) {
#pragma unroll
    for (int i = 0; i < 2; ++i) {
      int idx = i * 256 + tid;
      int r = idx >> 3, c = (idx & 7) << 3;
      *(s16x8*)&B1s[r][c] = *(const s16x8*)&B1T[(size_t)(jc * 64 + r) * 64 + c];
      *(s16x8*)&A2s[r][c] = *(const s16x8*)&A2T[(size_t)r * 2048 + jc * 64 + c];
    }
    __syncthreads();
    f32x4 ha[2];
    ha[0] = (f32x4){0.f, 0.f, 0.f, 0.f};
    ha[1] = (f32x4){0.f, 0.f, 0.f, 0.f};
#pragma unroll
    for (int kk = 0; kk < 2; ++kk) {
      const int kb_ = kk * 32 + hi * 8;
      s16x8 a = *(const s16x8*)&Us[wm + l16][kb_];
#pragma unroll
      for (int j = 0; j < 2; ++j) {
        s16x8 b = *(const s16x8*)&B1s[wn + j * 16 + l16][kb_];
        ha[j] = __builtin_amdgcn_mfma_f32_16x16x32_bf16(a, b, ha[j], 0, 0, 0);
      }
    }
#pragma unroll
    for (int j = 0; j < 2; ++j)
#pragma unroll
      for (int i = 0; i < 4; ++i)
        Hs[wm + hi * 4 + i][wn + j * 16 + l16] = f2bf(fmaxf(ha[j][i], 0.f));
    __syncthreads();
#pragma unroll
    for (int kk = 0; kk < 2; ++kk) {
      const int kb_ = kk * 32 + hi * 8;
      s16x8 a = *(const s16x8*)&Hs[wm + l16][kb_];
#pragma unroll
      for (int j = 0; j < 2; ++j) {
        s16x8 b = *(const s16x8*)&A2s[wn + j * 16 + l16][kb_];
        w2a[j] = __builtin_amdgcn_mfma_f32_16x16x32_bf16(a, b, w2a[j], 0, 0, 0);
      }
    }
    __syncthreads();
  }
#pragma unroll
  for (int j = 0; j < 2; ++j)
#pragma unroll
    for (int i = 0; i < 4; ++i)
      w2[(size_t)(m0 + wm + hi * 4 + i) * 64 + wn + j * 16 + l16] = f2bf(w2a[j][i]);
}

// ---------------- host launch ----------------
extern "C" void kernel_launch(void* const* d_in, const int* in_sizes, int n_in,
                              void* d_out, int out_size, void* d_ws, size_t ws_size,
                              hipStream_t stream) {
  const float* q = (const float*)d_in[0];
  const float* k = (const float*)d_in[1];
  const float* v = (const float*)d_in[2];
  const float* Wq = (const float*)d_in[3];
  const float* bq = (const float*)d_in[4];
  const float* Wk = (const float*)d_in[5];
  const float* bk = (const float*)d_in[6];
  const float* Wv = (const float*)d_in[7];
  const float* bv = (const float*)d_in[8];
  const float* Wo = (const float*)d_in[9];
  const float* bo = (const float*)d_in[10];
  const float* topk = (const float*)d_in[11];
  const float* A1 = (const float*)d_in[12];
  const float* B1 = (const float*)d_in[13];
  const float* A2 = (const float*)d_in[14];
  const float* B2 = (const float*)d_in[15];
  const float* g1 = (const float*)d_in[16];
  const float* be1 = (const float*)d_in[17];
  const float* g2 = (const float*)d_in[18];
  const float* be2 = (const float*)d_in[19];

  char* ws = (char*)d_ws;
  constexpr size_t SZ_TOK_BF = (size_t)8192 * 512 * 2;
  constexpr size_t SZ_W_BF = (size_t)512 * 512 * 2;
  constexpr size_t O_QB = 0;
  constexpr size_t O_KB = O_QB + SZ_TOK_BF;
  constexpr size_t O_VB = O_KB + SZ_TOK_BF;
  constexpr size_t O_QW = O_VB + SZ_TOK_BF;
  constexpr size_t O_KW = O_QW + SZ_TOK_BF;
  constexpr size_t O_VW = O_KW + SZ_TOK_BF;
  constexpr size_t O_WQT = O_VW + SZ_TOK_BF;
  constexpr size_t O_WKT = O_WQT + SZ_W_BF;
  constexpr size_t O_WVT = O_WKT + SZ_W_BF;
  constexpr size_t O_WOT = O_WVT + SZ_W_BF;
  constexpr size_t O_A1T = O_WOT + SZ_W_BF;
  constexpr size_t O_B1T = O_A1T + 65536;
  constexpr size_t O_A2T = O_B1T + 262144;
  constexpr size_t O_B2T = O_A2T + 262144;
  constexpr size_t O_AO = O_B2T + 65536;
  constexpr size_t O_SRCB = O_AO + SZ_TOK_BF;
  constexpr size_t O_W2 = O_SRCB + SZ_TOK_BF;

  u16* qb = (u16*)(ws + O_QB);
  u16* kb = (u16*)(ws + O_KB);
  u16* vb = (u16*)(ws + O_VB);
  u16* Qw_ = (u16*)(ws + O_QW);
  u16* Kw_ = (u16*)(ws + O_KW);
  u16* Vw_ = (u16*)(ws + O_VW);
  u16* WqT = (u16*)(ws + O_WQT);
  u16* WkT = (u16*)(ws + O_WKT);
  u16* WvT = (u16*)(ws + O_WVT);
  u16* WoT = (u16*)(ws + O_WOT);
  u16* A1T = (u16*)(ws + O_A1T);
  u16* B1T = (u16*)(ws + O_B1T);
  u16* A2T = (u16*)(ws + O_A2T);
  u16* B2T = (u16*)(ws + O_B2T);
  u16* ao = (u16*)(ws + O_AO);
  u16* srcb = (u16*)(ws + O_SRCB);
  u16* w2 = (u16*)(ws + O_W2);

  // 1) conversions + weight transposes
  prep_all<<<17664, 256, 0, stream>>>(q, k, v, Wq, Wk, Wv, Wo, A1, B1, A2, B2,
                                      qb, kb, vb, WqT, WkT, WvT, WoT, A1T, B1T, A2T, B2T);

  // 2) QKV projections (one launch, 768 blocks)
  qkv_fused<<<dim3(4, 64, 3), 256, 0, stream>>>(qb, kb, vb, WqT, WkT, WvT,
                                                bq, bk, bv, Qw_, Kw_, Vw_);

  // 3) fused attention
  attn_kernel<<<dim3(32, 64), 512, 0, stream>>>(Qw_, Kw_, Vw_, topk, ao);

  // 4) Wo + bias + residual(q) + LN1 -> srcb
  gemm_ln<true><<<512, 256, 0, stream>>>(ao, WoT, bo, q, nullptr, g1, be1, nullptr, srcb);

  // 5) fused FFN inner: w2 = relu(srcb@A1@B1)@A2
  ffn3<<<256, 256, 0, stream>>>(srcb, A1T, B1T, A2T, w2);

  // 6) B2 + residual(srcb) + LN2 -> d_out
  gemm_ln<false><<<512, 256, 0, stream>>>(w2, B2T, nullptr, nullptr, srcb, g2, be2,
                                          (float*)d_out, nullptr);
}